// Round 2
// baseline (636.302 us; speedup 1.0000x reference)
//
#include <hip/hip_runtime.h>
#include <math.h>

#define N_NODES   500000
#define N_GRAPHS  50000
#define N_EDGES   4000000
#define MAIN_WAVES 8192         // k_main: 2048 blocks x 4 waves, grid-stride

// ---- workspace layout (bytes) ----
#define CNT_OFF   0u            // u32[5,000,000] edge count matrices
#define CHW_OFF   20000000u     // f32[170*64]  champ_table @ W1[0:32]
#define ROW_OFF   20043520u     // f32[10*64]   role_table @ W1[32:40]
#define P1S_OFF   20046080u     // f32[128*64]
#define P1Q_OFF   20078848u     // f32[128*64]
#define P2S_OFF   20111616u     // f32[128*32]
#define P2Q_OFF   20128000u     // f32[128*32]
#define SC_OFF    20144384u     // f32[192]
#define ZB_OFF    20145152u     // f32[50000*32] pre-BN2 fc1 output
#define WM_OFF    26545152u     // f32[50000*120] Wmat rows padded to 12
#define U2_OFF    50545152u     // f32[8192*640]  per-wave u2 slots
#define GP_OFF    71516672u     // f32[8192*64]   per-wave pool slots
#define ZERO_BYTES 20144384u    // zero cnt + partial-stat regions

// ---------- tables: champW1, roleW1 ----------
__global__ void k_tables(const float* __restrict__ champ, const float* __restrict__ role,
                         const float* __restrict__ W1,
                         float* __restrict__ chW, float* __restrict__ roW) {
    int t = blockIdx.x * blockDim.x + threadIdx.x;
    if (t < 170 * 64) {
        int c = t >> 6, j = t & 63;
        float s = 0.f;
        #pragma unroll
        for (int k = 0; k < 32; k++) s += champ[c * 32 + k] * W1[k * 64 + j];
        chW[t] = s;
    } else if (t < 170 * 64 + 10 * 64) {
        int t2 = t - 170 * 64;
        int r = t2 >> 6, j = t2 & 63;
        float s = 0.f;
        #pragma unroll
        for (int k = 0; k < 8; k++) s += role[r * 8 + k] * W1[(32 + k) * 64 + j];
        roW[t2] = s;
    }
}

// ---------- bin edges into per-graph 10x10 counts ----------
__global__ void k_edges(const int* __restrict__ ei, unsigned* __restrict__ cnt) {
    int stride = gridDim.x * blockDim.x;
    for (int e = blockIdx.x * blockDim.x + threadIdx.x; e < N_EDGES; e += stride) {
        unsigned s = (unsigned)ei[e];
        unsigned d = (unsigned)ei[N_EDGES + e];
        unsigned g  = d / 10u;
        atomicAdd(&cnt[g * 100u + (d % 10u) * 10u + (s % 10u)], 1u);
    }
}

// ---------- build normalized 10x12(padded) adjacency per graph -> global ----------
__global__ __launch_bounds__(256) void k_wmat(const unsigned* __restrict__ cnt,
                                              float* __restrict__ wmat) {
    __shared__ float c_lds[4][100];
    __shared__ float dinv_lds[4][12];
    const int w = threadIdx.x >> 6, lane = threadIdx.x & 63;
    const int g = blockIdx.x * 4 + w;

    c_lds[w][lane] = (float)cnt[g * 100 + lane];
    if (lane < 36) c_lds[w][64 + lane] = (float)cnt[g * 100 + 64 + lane];
    __syncthreads();
    if (lane < 10) {
        float s = 1.f;
        #pragma unroll
        for (int v = 0; v < 10; v++) s += c_lds[w][lane * 10 + v];
        dinv_lds[w][lane] = rsqrtf(s);
    }
    __syncthreads();
    #pragma unroll
    for (int r = 0; r < 2; r++) {
        int t = lane + r * 64;
        if (t < 120) {
            int u = t / 12, v = t - u * 12;
            float val = 0.f;
            if (v < 10)
                val = (c_lds[w][u * 10 + v] + (u == v ? 1.f : 0.f)) *
                      dinv_lds[w][u] * dinv_lds[w][v];
            wmat[g * 120 + t] = val;
        }
    }
}

// ---------- pass1: a1 = Wmat@hw + b1 via SGPR Wmat ; BN1 stats ----------
__global__ __launch_bounds__(256) void k_pass1(
    const int* __restrict__ x, const float* __restrict__ wmat,
    const float* __restrict__ chW, const float* __restrict__ roW,
    const float* __restrict__ W1, const float* __restrict__ b1,
    float* __restrict__ p1s, float* __restrict__ p1q)
{
    const int lane = threadIdx.x & 63;
    const int g = __builtin_amdgcn_readfirstlane(blockIdx.x * 4 + (threadIdx.x >> 6));
    const int* xg = x + g * 30;           // uniform -> s_load
    const float* wm = wmat + g * 120;     // uniform -> s_load

    const float w1t = W1[40 * 64 + lane];
    float hw[10];
    #pragma unroll
    for (int u = 0; u < 10; u++) {
        int cu = xg[u * 3 + 0];
        int ru = xg[u * 3 + 1];
        float tm = (float)xg[u * 3 + 2];
        hw[u] = chW[cu * 64 + lane] + roW[ru * 64 + lane] + tm * w1t;
    }
    const float b1v = b1[lane];
    float s = 0.f, ss = 0.f;
    #pragma unroll
    for (int u = 0; u < 10; u++) {
        float a = b1v;
        #pragma unroll
        for (int v = 0; v < 10; v++) a = fmaf(wm[u * 12 + v], hw[v], a);
        s += a; ss += a * a;
    }
    int slot = g & 127;
    atomicAdd(&p1s[slot * 64 + lane], s);
    atomicAdd(&p1q[slot * 64 + lane], ss);
}

__global__ void k_fin1(const float* __restrict__ p1s, const float* __restrict__ p1q,
                       const float* __restrict__ gamma, const float* __restrict__ beta,
                       float* __restrict__ sc) {
    int j = threadIdx.x;  // 64
    double s = 0.0, q = 0.0;
    for (int k = 0; k < 128; k++) { s += p1s[k * 64 + j]; q += p1q[k * 64 + j]; }
    double mu = s / (double)N_NODES;
    double var = q / (double)N_NODES - mu * mu;
    float scl = gamma[j] * rsqrtf((float)var + 1e-5f);
    sc[j] = scl;
    sc[64 + j] = beta[j] - (float)mu * scl;
}

// ---------- main fused pass: a1,BN1,relu,u2, layer2 GEMM, pool, fc1, BN2 stats ----------
__global__ __launch_bounds__(256) void k_main(
    const int* __restrict__ x, const float* __restrict__ wmat,
    const float* __restrict__ chW, const float* __restrict__ roW,
    const float* __restrict__ W1, const float* __restrict__ b1,
    const float* __restrict__ sc,
    const float* __restrict__ W2, const float* __restrict__ b2,
    const float* __restrict__ fc1W, const float* __restrict__ fc1b,
    float* u2g, float* gpg,                      // NOT restrict: RAW round-trips
    float* __restrict__ zbuf, float* __restrict__ p2s, float* __restrict__ p2q)
{
    const int lane = threadIdx.x & 63;
    const int wid = __builtin_amdgcn_readfirstlane(blockIdx.x * 4 + (threadIdx.x >> 6));

    float w2c[64];
    #pragma unroll
    for (int k = 0; k < 64; k++) w2c[k] = W2[k * 64 + lane];

    float* u2s = u2g + (size_t)wid * 640;
    float* gps = gpg + (size_t)wid * 64;
    const float w1t = W1[40 * 64 + lane];
    const float b1v = b1[lane];
    const float sc1 = sc[lane], sf1 = sc[64 + lane];
    const float b2v = b2[lane];
    const int jj = lane & 31;
    const float fc1bv = fc1b[jj];

    for (int g = wid; g < N_GRAPHS; g += MAIN_WAVES) {
        const int* xg = x + g * 30;
        const float* wm = wmat + g * 120;

        float hw[10];
        #pragma unroll
        for (int u = 0; u < 10; u++) {
            int cu = xg[u * 3 + 0];
            int ru = xg[u * 3 + 1];
            float tm = (float)xg[u * 3 + 2];
            hw[u] = chW[cu * 64 + lane] + roW[ru * 64 + lane] + tm * w1t;
        }
        float h1[10];
        #pragma unroll
        for (int u = 0; u < 10; u++) {
            float a = b1v;
            #pragma unroll
            for (int v = 0; v < 10; v++) a = fmaf(wm[u * 12 + v], hw[v], a);
            h1[u] = fmaxf(fmaf(a, sc1, sf1), 0.f);
        }
        // u2 = Wmat @ h1 -> per-wave global slot (broadcast staging via L1/L2)
        #pragma unroll
        for (int u = 0; u < 10; u++) {
            float t = 0.f;
            #pragma unroll
            for (int v = 0; v < 10; v++) t = fmaf(wm[u * 12 + v], h1[v], t);
            u2s[u * 64 + lane] = t;
        }
        // a2 = u2 @ W2 (+b2, relu, mean-pool) ; u2 rows read back wave-uniform
        const float4* up = (const float4*)u2s;
        float gp = 0.f;
        #pragma unroll
        for (int u = 0; u < 10; u++) {
            float a0 = 0.f, a1 = 0.f, a2 = 0.f, a3 = 0.f;
            #pragma unroll
            for (int q = 0; q < 16; q++) {
                float4 r = up[u * 16 + q];
                a0 = fmaf(r.x, w2c[4 * q + 0], a0);
                a1 = fmaf(r.y, w2c[4 * q + 1], a1);
                a2 = fmaf(r.z, w2c[4 * q + 2], a2);
                a3 = fmaf(r.w, w2c[4 * q + 3], a3);
            }
            gp += fmaxf(a0 + a1 + a2 + a3 + b2v, 0.f);
        }
        gp *= 0.1f;
        gps[lane] = gp;
        // fc1: z[jj] = sum_k g[k] * fc1W[k][jj] (uniform read-back of g)
        const float4* gq = (const float4*)gps;
        float z0 = 0.f, z1 = 0.f, z2 = 0.f, z3 = 0.f;
        #pragma unroll
        for (int q = 0; q < 16; q++) {
            float4 r = gq[q];
            z0 = fmaf(r.x, fc1W[(4 * q + 0) * 32 + jj], z0);
            z1 = fmaf(r.y, fc1W[(4 * q + 1) * 32 + jj], z1);
            z2 = fmaf(r.z, fc1W[(4 * q + 2) * 32 + jj], z2);
            z3 = fmaf(r.w, fc1W[(4 * q + 3) * 32 + jj], z3);
        }
        float zv = z0 + z1 + z2 + z3 + fc1bv;
        if (lane < 32) {
            zbuf[g * 32 + jj] = zv;
            int slot = g & 127;
            atomicAdd(&p2s[slot * 32 + jj], zv);
            atomicAdd(&p2q[slot * 32 + jj], zv * zv);
        }
    }
}

__global__ void k_fin2(const float* __restrict__ p2s, const float* __restrict__ p2q,
                       const float* __restrict__ gamma, const float* __restrict__ beta,
                       float* __restrict__ sc) {
    int j = threadIdx.x;  // 32
    double s = 0.0, q = 0.0;
    for (int k = 0; k < 128; k++) { s += p2s[k * 32 + j]; q += p2q[k * 32 + j]; }
    double mu = s / (double)N_GRAPHS;
    double var = q / (double)N_GRAPHS - mu * mu;
    float scl = gamma[j] * rsqrtf((float)var + 1e-5f);
    sc[128 + j] = scl;
    sc[160 + j] = beta[j] - (float)mu * scl;
}

__global__ __launch_bounds__(256) void k_pass3(
    const float* __restrict__ z, const float* __restrict__ sc,
    const float* __restrict__ fc2W, const float* __restrict__ fc2b,
    float* __restrict__ out)
{
    int t = blockIdx.x * blockDim.x + threadIdx.x;
    int g = t >> 5, j = t & 31;
    float y = fmaxf(fmaf(z[g * 32 + j], sc[128 + j], sc[160 + j]), 0.f);
    float acc = y * fc2W[j];
    #pragma unroll
    for (int off = 16; off > 0; off >>= 1) acc += __shfl_xor(acc, off, 32);
    if (j == 0) out[g] = 1.0f / (1.0f + __expf(-(acc + fc2b[0])));
}

extern "C" void kernel_launch(void* const* d_in, const int* in_sizes, int n_in,
                              void* d_out, int out_size, void* d_ws, size_t ws_size,
                              hipStream_t stream) {
    const int*   x      = (const int*)d_in[0];
    const int*   ei     = (const int*)d_in[1];
    const float* champ  = (const float*)d_in[3];
    const float* role   = (const float*)d_in[4];
    const float* W1     = (const float*)d_in[5];
    const float* b1     = (const float*)d_in[6];
    const float* gamma1 = (const float*)d_in[7];
    const float* beta1  = (const float*)d_in[8];
    const float* W2     = (const float*)d_in[9];
    const float* b2     = (const float*)d_in[10];
    const float* fc1W   = (const float*)d_in[11];
    const float* fc1b   = (const float*)d_in[12];
    const float* gamma2 = (const float*)d_in[13];
    const float* beta2  = (const float*)d_in[14];
    const float* fc2W   = (const float*)d_in[15];
    const float* fc2b   = (const float*)d_in[16];
    float* out = (float*)d_out;

    char* ws = (char*)d_ws;
    unsigned* cnt  = (unsigned*)(ws + CNT_OFF);
    float* chW  = (float*)(ws + CHW_OFF);
    float* roW  = (float*)(ws + ROW_OFF);
    float* p1s  = (float*)(ws + P1S_OFF);
    float* p1q  = (float*)(ws + P1Q_OFF);
    float* p2s  = (float*)(ws + P2S_OFF);
    float* p2q  = (float*)(ws + P2Q_OFF);
    float* scb  = (float*)(ws + SC_OFF);
    float* zbuf = (float*)(ws + ZB_OFF);
    float* wmat = (float*)(ws + WM_OFF);
    float* u2g  = (float*)(ws + U2_OFF);
    float* gpg  = (float*)(ws + GP_OFF);

    hipMemsetAsync(ws, 0, ZERO_BYTES, stream);
    k_tables<<<45, 256, 0, stream>>>(champ, role, W1, chW, roW);
    k_edges<<<2048, 256, 0, stream>>>(ei, cnt);
    k_wmat<<<N_GRAPHS / 4, 256, 0, stream>>>(cnt, wmat);
    k_pass1<<<N_GRAPHS / 4, 256, 0, stream>>>(x, wmat, chW, roW, W1, b1, p1s, p1q);
    k_fin1<<<1, 64, 0, stream>>>(p1s, p1q, gamma1, beta1, scb);
    k_main<<<MAIN_WAVES / 4, 256, 0, stream>>>(x, wmat, chW, roW, W1, b1, scb,
                                               W2, b2, fc1W, fc1b,
                                               u2g, gpg, zbuf, p2s, p2q);
    k_fin2<<<1, 32, 0, stream>>>(p2s, p2q, gamma2, beta2, scb);
    k_pass3<<<N_GRAPHS / 8, 256, 0, stream>>>(zbuf, scb, fc2W, fc2b, out);
}

// Round 4
// 467.737 us; speedup vs baseline: 1.3604x; 1.3604x over previous
//
#include <hip/hip_runtime.h>
#include <math.h>

typedef __attribute__((ext_vector_type(8))) short bf16x8;
typedef __attribute__((ext_vector_type(4))) float f32x4;

#define N_NODES   500000
#define N_GRAPHS  50000
#define N_EDGES   4000000

// ---- workspace layout (bytes) ----
#define CNT_OFF   0u            // u32[5,000,000] edge count matrices
#define CHW_OFF   20000000u     // f32[170*64]  champ_table @ W1[0:32]
#define ROW_OFF   20043520u     // f32[10*64]   role_table @ W1[32:40]
#define P1S_OFF   20046080u     // f32[128*64]
#define P1Q_OFF   20078848u     // f32[128*64]
#define P2S_OFF   20111616u     // f32[128*32]
#define P2Q_OFF   20128000u     // f32[128*32]
#define SC_OFF    20144384u     // f32[192]
#define ZB_OFF    20145152u     // f32[50000*32] pre-BN2 fc1 output
#define WM_OFF    26545152u     // f32[50000*120] Wmat rows padded to 12
#define ZERO_BYTES 20144384u

// RNE round f32 -> bf16 bits
__device__ __forceinline__ unsigned short rne_bf16(float x) {
    unsigned b = __builtin_bit_cast(unsigned, x);
    return (unsigned short)((b + 0x7fffu + ((b >> 16) & 1u)) >> 16);
}
// split 8 f32 into hi/lo bf16x8 (x ~= hi + lo to ~2^-18 rel)
__device__ __forceinline__ void split8(const float v[8], bf16x8 &h, bf16x8 &l) {
    #pragma unroll
    for (int e = 0; e < 8; e++) {
        unsigned short hs = rne_bf16(v[e]);
        float hf = __builtin_bit_cast(float, ((unsigned)hs) << 16);
        h[e] = (short)hs;
        l[e] = (short)rne_bf16(v[e] - hf);
    }
}

// ---------- tables: champW1, roleW1 ----------
__global__ void k_tables(const float* __restrict__ champ, const float* __restrict__ role,
                         const float* __restrict__ W1,
                         float* __restrict__ chW, float* __restrict__ roW) {
    int t = blockIdx.x * blockDim.x + threadIdx.x;
    if (t < 170 * 64) {
        int c = t >> 6, j = t & 63;
        float s = 0.f;
        #pragma unroll
        for (int k = 0; k < 32; k++) s += champ[c * 32 + k] * W1[k * 64 + j];
        chW[t] = s;
    } else if (t < 170 * 64 + 10 * 64) {
        int t2 = t - 170 * 64;
        int r = t2 >> 6, j = t2 & 63;
        float s = 0.f;
        #pragma unroll
        for (int k = 0; k < 8; k++) s += role[r * 8 + k] * W1[(32 + k) * 64 + j];
        roW[t2] = s;
    }
}

// ---------- bin edges into per-graph 10x10 counts ----------
__global__ void k_edges(const int* __restrict__ ei, unsigned* __restrict__ cnt) {
    int stride = gridDim.x * blockDim.x;
    for (int e = blockIdx.x * blockDim.x + threadIdx.x; e < N_EDGES; e += stride) {
        unsigned s = (unsigned)ei[e];
        unsigned d = (unsigned)ei[N_EDGES + e];
        unsigned g  = d / 10u;
        atomicAdd(&cnt[g * 100u + (d % 10u) * 10u + (s % 10u)], 1u);
    }
}

// ---------- build normalized 10x12(padded) adjacency per graph -> global ----------
__global__ __launch_bounds__(256) void k_wmat(const unsigned* __restrict__ cnt,
                                              float* __restrict__ wmat) {
    __shared__ float c_lds[4][100];
    __shared__ float dinv_lds[4][12];
    const int w = threadIdx.x >> 6, lane = threadIdx.x & 63;
    const int g = blockIdx.x * 4 + w;

    c_lds[w][lane] = (float)cnt[g * 100 + lane];
    if (lane < 36) c_lds[w][64 + lane] = (float)cnt[g * 100 + 64 + lane];
    __syncthreads();
    if (lane < 10) {
        float s = 1.f;
        #pragma unroll
        for (int v = 0; v < 10; v++) s += c_lds[w][lane * 10 + v];
        dinv_lds[w][lane] = rsqrtf(s);
    }
    __syncthreads();
    #pragma unroll
    for (int r = 0; r < 2; r++) {
        int t = lane + r * 64;
        if (t < 120) {
            int u = t / 12, v = t - u * 12;
            float val = 0.f;
            if (v < 10)
                val = (c_lds[w][u * 10 + v] + (u == v ? 1.f : 0.f)) *
                      dinv_lds[w][u] * dinv_lds[w][v];
            wmat[g * 120 + t] = val;
        }
    }
}

// ---------- pass1: a1 = Wmat@hw + b1 via SGPR Wmat ; BN1 stats ----------
__global__ __launch_bounds__(256) void k_pass1(
    const int* __restrict__ x, const float* __restrict__ wmat,
    const float* __restrict__ chW, const float* __restrict__ roW,
    const float* __restrict__ W1, const float* __restrict__ b1,
    float* __restrict__ p1s, float* __restrict__ p1q)
{
    const int lane = threadIdx.x & 63;
    const int g = __builtin_amdgcn_readfirstlane(blockIdx.x * 4 + (threadIdx.x >> 6));
    const int* xg = x + g * 30;           // uniform -> s_load
    const float* wm = wmat + g * 120;     // uniform -> s_load

    const float w1t = W1[40 * 64 + lane];
    float hw[10];
    #pragma unroll
    for (int u = 0; u < 10; u++) {
        int cu = xg[u * 3 + 0];
        int ru = xg[u * 3 + 1];
        float tm = (float)xg[u * 3 + 2];
        hw[u] = chW[cu * 64 + lane] + roW[ru * 64 + lane] + tm * w1t;
    }
    const float b1v = b1[lane];
    float s = 0.f, ss = 0.f;
    #pragma unroll
    for (int u = 0; u < 10; u++) {
        float a = b1v;
        #pragma unroll
        for (int v = 0; v < 10; v++) a = fmaf(wm[u * 12 + v], hw[v], a);
        s += a; ss += a * a;
    }
    int slot = g & 127;
    atomicAdd(&p1s[slot * 64 + lane], s);
    atomicAdd(&p1q[slot * 64 + lane], ss);
}

__global__ void k_fin1(const float* __restrict__ p1s, const float* __restrict__ p1q,
                       const float* __restrict__ gamma, const float* __restrict__ beta,
                       float* __restrict__ sc) {
    int j = threadIdx.x;  // 64
    double s = 0.0, q = 0.0;
    for (int k = 0; k < 128; k++) { s += p1s[k * 64 + j]; q += p1q[k * 64 + j]; }
    double mu = s / (double)N_NODES;
    double var = q / (double)N_NODES - mu * mu;
    float scl = gamma[j] * rsqrtf((float)var + 1e-5f);
    sc[j] = scl;
    sc[64 + j] = beta[j] - (float)mu * scl;
}

// ---------- main fused pass: MFMA for a2 GEMM and fc1 ----------
// wave = 16 graphs (50000 = 3125 * 16). Per-wave LDS tiles [16][68] f32 for
// u2 (MFMA A) and pooled G (fc1 A). W2 frags pre-split to block LDS.
// MFMA 16x16x32 bf16: A/B share the same (lane-group,elem)->k bijection, so
// any consistent k-permutation contracts correctly; C: col=lane&15, row=4q+reg.
__global__ __launch_bounds__(256) void k_main(
    const int* __restrict__ x, const float* __restrict__ wmat,
    const float* __restrict__ chW, const float* __restrict__ roW,
    const float* __restrict__ W1, const float* __restrict__ b1,
    const float* __restrict__ sc,
    const float* __restrict__ W2, const float* __restrict__ b2,
    const float* __restrict__ fc1W, const float* __restrict__ fc1b,
    float* __restrict__ zbuf, float* __restrict__ p2s, float* __restrict__ p2q)
{
    __shared__ bf16x8 w2f[2][2][4][64];   // [hi/lo][ks][t][lane] = 16 KB
    __shared__ float  stage[4][2][1088];  // [wave][u2|G][16*68] = 34.8 KB

    const int tid = threadIdx.x, w = tid >> 6, lane = tid & 63;
    const int q = lane >> 4, c = lane & 15;

    // wave 0 pre-splits W2 into MFMA B-fragments (hi/lo bf16)
    if (w == 0) {
        #pragma unroll
        for (int ks = 0; ks < 2; ks++)
        #pragma unroll
        for (int t = 0; t < 4; t++) {
            float v[8];
            #pragma unroll
            for (int e = 0; e < 8; e++) {
                int k = 32 * ks + (e < 4 ? 4 * q + e : 16 + 4 * q + (e - 4));
                v[e] = W2[k * 64 + 16 * t + c];
            }
            bf16x8 h, l; split8(v, h, l);
            w2f[0][ks][t][lane] = h;
            w2f[1][ks][t][lane] = l;
        }
    }
    __syncthreads();

    const int wid = __builtin_amdgcn_readfirstlane((int)blockIdx.x * 4 + w);
    if (wid >= N_GRAPHS / 16) return;
    const int g0 = wid * 16;

    float* up = &stage[w][0][0];
    float* Gp = &stage[w][1][0];
    // zero A pad rows 10..15 once (dwords 680..1087)
    for (int i = lane; i < 408; i += 64) up[680 + i] = 0.f;

    // fc1W B-fragments in registers (2 N-tiles x 2 K-steps, hi/lo)
    bf16x8 f1h[2][2], f1l[2][2];
    #pragma unroll
    for (int ks = 0; ks < 2; ks++)
    #pragma unroll
    for (int t = 0; t < 2; t++) {
        float v[8];
        #pragma unroll
        for (int e = 0; e < 8; e++) {
            int k = 32 * ks + (e < 4 ? 4 * q + e : 16 + 4 * q + (e - 4));
            v[e] = fc1W[k * 32 + 16 * t + c];
        }
        split8(v, f1h[t][ks], f1l[t][ks]);
    }

    const float w1t = W1[40 * 64 + lane];
    const float b1v = b1[lane];
    const float sc1 = sc[lane], sf1 = sc[64 + lane];
    float b2v[4];
    #pragma unroll
    for (int t = 0; t < 4; t++) b2v[t] = b2[16 * t + c];
    float f1bv[2];
    #pragma unroll
    for (int t = 0; t < 2; t++) f1bv[t] = fc1b[16 * t + c];

    f32x4 facc[2] = {f32x4{0.f,0.f,0.f,0.f}, f32x4{0.f,0.f,0.f,0.f}};

    for (int gi = 0; gi < 16; gi++) {
        const int g = g0 + gi;
        const int* xg = x + g * 30;           // uniform -> s_load
        const float* wm = wmat + g * 120;     // uniform -> s_load

        float hw[10];
        #pragma unroll
        for (int u = 0; u < 10; u++) {
            int cu = xg[u * 3 + 0];
            int ru = xg[u * 3 + 1];
            float tm = (float)xg[u * 3 + 2];
            hw[u] = chW[cu * 64 + lane] + roW[ru * 64 + lane] + tm * w1t;
        }
        float h1[10];
        #pragma unroll
        for (int u = 0; u < 10; u++) {
            float a = b1v;
            #pragma unroll
            for (int v2 = 0; v2 < 10; v2++) a = fmaf(wm[u * 12 + v2], hw[v2], a);
            h1[u] = fmaxf(fmaf(a, sc1, sf1), 0.f);
        }
        // u2 = Wmat @ h1 -> per-wave LDS tile (row stride 68 dw: 16B-aligned, 2-way banks)
        #pragma unroll
        for (int u = 0; u < 10; u++) {
            float t = 0.f;
            #pragma unroll
            for (int v2 = 0; v2 < 10; v2++) t = fmaf(wm[u * 12 + v2], h1[v2], t);
            up[u * 68 + lane] = t;
        }
        // a2 = u2 @ W2 via 4-product split MFMA
        f32x4 acc[4] = {f32x4{0.f,0.f,0.f,0.f}, f32x4{0.f,0.f,0.f,0.f},
                        f32x4{0.f,0.f,0.f,0.f}, f32x4{0.f,0.f,0.f,0.f}};
        const float4* rowp = (const float4*)(up + c * 68);
        #pragma unroll
        for (int ks = 0; ks < 2; ks++) {
            float4 A0 = rowp[8 * ks + q];
            float4 A1 = rowp[8 * ks + 4 + q];
            float av[8] = {A0.x, A0.y, A0.z, A0.w, A1.x, A1.y, A1.z, A1.w};
            bf16x8 ah, al; split8(av, ah, al);
            #pragma unroll
            for (int t = 0; t < 4; t++) {
                bf16x8 bh = w2f[0][ks][t][lane];
                bf16x8 bl = w2f[1][ks][t][lane];
                acc[t] = __builtin_amdgcn_mfma_f32_16x16x32_bf16(ah, bh, acc[t], 0, 0, 0);
                acc[t] = __builtin_amdgcn_mfma_f32_16x16x32_bf16(ah, bl, acc[t], 0, 0, 0);
                acc[t] = __builtin_amdgcn_mfma_f32_16x16x32_bf16(al, bh, acc[t], 0, 0, 0);
                acc[t] = __builtin_amdgcn_mfma_f32_16x16x32_bf16(al, bl, acc[t], 0, 0, 0);
            }
        }
        // relu + masked mean-pool; C rows are nodes m = 4q+r
        #pragma unroll
        for (int t = 0; t < 4; t++) {
            float pt = 0.f;
            #pragma unroll
            for (int r = 0; r < 4; r++) {
                int m = 4 * q + r;
                float val = fmaxf(acc[t][r] + b2v[t], 0.f);
                pt += (m < 10) ? val : 0.f;
            }
            pt += __shfl_xor(pt, 16);
            pt += __shfl_xor(pt, 32);
            pt *= 0.1f;
            if (lane < 16) Gp[gi * 68 + 16 * t + lane] = pt;
        }
    }

    // fc1 over the 16 pooled vectors via split MFMA (A rows = graphs)
    const float4* grow = (const float4*)(Gp + c * 68);
    #pragma unroll
    for (int ks = 0; ks < 2; ks++) {
        float4 G0 = grow[8 * ks + q];
        float4 G1 = grow[8 * ks + 4 + q];
        float gv[8] = {G0.x, G0.y, G0.z, G0.w, G1.x, G1.y, G1.z, G1.w};
        bf16x8 gh, gl; split8(gv, gh, gl);
        #pragma unroll
        for (int t = 0; t < 2; t++) {
            facc[t] = __builtin_amdgcn_mfma_f32_16x16x32_bf16(gh, f1h[t][ks], facc[t], 0, 0, 0);
            facc[t] = __builtin_amdgcn_mfma_f32_16x16x32_bf16(gh, f1l[t][ks], facc[t], 0, 0, 0);
            facc[t] = __builtin_amdgcn_mfma_f32_16x16x32_bf16(gl, f1h[t][ks], facc[t], 0, 0, 0);
            facc[t] = __builtin_amdgcn_mfma_f32_16x16x32_bf16(gl, f1l[t][ks], facc[t], 0, 0, 0);
        }
    }
    // z + BN2 stats straight from C regs: row = graph 4q+r, col = 16t+c
    #pragma unroll
    for (int t = 0; t < 2; t++)
    #pragma unroll
    for (int r = 0; r < 4; r++) {
        int gg = g0 + 4 * q + r;
        float zv = facc[t][r] + f1bv[t];
        zbuf[gg * 32 + 16 * t + c] = zv;
        int slot = gg & 127;
        atomicAdd(&p2s[slot * 32 + 16 * t + c], zv);
        atomicAdd(&p2q[slot * 32 + 16 * t + c], zv * zv);
    }
}

__global__ void k_fin2(const float* __restrict__ p2s, const float* __restrict__ p2q,
                       const float* __restrict__ gamma, const float* __restrict__ beta,
                       float* __restrict__ sc) {
    int j = threadIdx.x;  // 32
    double s = 0.0, q = 0.0;
    for (int k = 0; k < 128; k++) { s += p2s[k * 32 + j]; q += p2q[k * 32 + j]; }
    double mu = s / (double)N_GRAPHS;
    double var = q / (double)N_GRAPHS - mu * mu;
    float scl = gamma[j] * rsqrtf((float)var + 1e-5f);
    sc[128 + j] = scl;
    sc[160 + j] = beta[j] - (float)mu * scl;
}

__global__ __launch_bounds__(256) void k_pass3(
    const float* __restrict__ z, const float* __restrict__ sc,
    const float* __restrict__ fc2W, const float* __restrict__ fc2b,
    float* __restrict__ out)
{
    int t = blockIdx.x * blockDim.x + threadIdx.x;
    int g = t >> 5, j = t & 31;
    float y = fmaxf(fmaf(z[g * 32 + j], sc[128 + j], sc[160 + j]), 0.f);
    float acc = y * fc2W[j];
    #pragma unroll
    for (int off = 16; off > 0; off >>= 1) acc += __shfl_xor(acc, off, 32);
    if (j == 0) out[g] = 1.0f / (1.0f + __expf(-(acc + fc2b[0])));
}

extern "C" void kernel_launch(void* const* d_in, const int* in_sizes, int n_in,
                              void* d_out, int out_size, void* d_ws, size_t ws_size,
                              hipStream_t stream) {
    const int*   x      = (const int*)d_in[0];
    const int*   ei     = (const int*)d_in[1];
    const float* champ  = (const float*)d_in[3];
    const float* role   = (const float*)d_in[4];
    const float* W1     = (const float*)d_in[5];
    const float* b1     = (const float*)d_in[6];
    const float* gamma1 = (const float*)d_in[7];
    const float* beta1  = (const float*)d_in[8];
    const float* W2     = (const float*)d_in[9];
    const float* b2     = (const float*)d_in[10];
    const float* fc1W   = (const float*)d_in[11];
    const float* fc1b   = (const float*)d_in[12];
    const float* gamma2 = (const float*)d_in[13];
    const float* beta2  = (const float*)d_in[14];
    const float* fc2W   = (const float*)d_in[15];
    const float* fc2b   = (const float*)d_in[16];
    float* out = (float*)d_out;

    char* ws = (char*)d_ws;
    unsigned* cnt  = (unsigned*)(ws + CNT_OFF);
    float* chW  = (float*)(ws + CHW_OFF);
    float* roW  = (float*)(ws + ROW_OFF);
    float* p1s  = (float*)(ws + P1S_OFF);
    float* p1q  = (float*)(ws + P1Q_OFF);
    float* p2s  = (float*)(ws + P2S_OFF);
    float* p2q  = (float*)(ws + P2Q_OFF);
    float* scb  = (float*)(ws + SC_OFF);
    float* zbuf = (float*)(ws + ZB_OFF);
    float* wmat = (float*)(ws + WM_OFF);

    hipMemsetAsync(ws, 0, ZERO_BYTES, stream);
    k_tables<<<45, 256, 0, stream>>>(champ, role, W1, chW, roW);
    k_edges<<<2048, 256, 0, stream>>>(ei, cnt);
    k_wmat<<<N_GRAPHS / 4, 256, 0, stream>>>(cnt, wmat);
    k_pass1<<<N_GRAPHS / 4, 256, 0, stream>>>(x, wmat, chW, roW, W1, b1, p1s, p1q);
    k_fin1<<<1, 64, 0, stream>>>(p1s, p1q, gamma1, beta1, scb);
    k_main<<<(N_GRAPHS / 16 + 3) / 4, 256, 0, stream>>>(x, wmat, chW, roW, W1, b1, scb,
                                                        W2, b2, fc1W, fc1b,
                                                        zbuf, p2s, p2q);
    k_fin2<<<1, 32, 0, stream>>>(p2s, p2q, gamma2, beta2, scb);
    k_pass3<<<N_GRAPHS / 8, 256, 0, stream>>>(zbuf, scb, fc2W, fc2b, out);
}

// Round 5
// 410.771 us; speedup vs baseline: 1.5490x; 1.1387x over previous
//
#include <hip/hip_runtime.h>
#include <math.h>

typedef __attribute__((ext_vector_type(8))) short bf16x8;
typedef __attribute__((ext_vector_type(4))) float f32x4;

#define N_NODES   500000
#define N_GRAPHS  50000
#define N_EDGES   4000000

// ---- workspace layout (bytes), all 16B aligned ----
#define CNT_OFF   0u          // u32[25][50000] packed 4xu8 counts, transposed
#define P1S_OFF   5000000u    // f32[128*64]
#define P1Q_OFF   5032768u    // f32[128*64]
#define P2S_OFF   5065536u    // f32[128*32]
#define P2Q_OFF   5081920u    // f32[128*32]
#define ZERO_BYTES 5098304u   // memset covers cnt + all partial-stat slots
#define CHW_OFF   5098304u    // f32[170*64]
#define ROW_OFF   5141824u    // f32[10*64]
#define W2F_OFF   5144384u    // bf16x8[16][64]  W2 frags [prod][ks][t]
#define F1F_OFF   5160768u    // bf16x8[8][64]   fc1W frags [prod][ks][t]
#define SC_OFF    5168960u    // f32[192]
#define ZB_OFF    5169728u    // f32[50000*32]
#define WM_OFF    11569728u   // f32[50000*120]
#define G_OFF     35569728u   // f32[50000*64] pooled graph vectors

// RNE round f32 -> bf16 bits
__device__ __forceinline__ unsigned short rne_bf16(float x) {
    unsigned b = __builtin_bit_cast(unsigned, x);
    return (unsigned short)((b + 0x7fffu + ((b >> 16) & 1u)) >> 16);
}
// split 8 f32 into hi/lo bf16x8 (x ~= hi + lo to ~2^-17 rel)
__device__ __forceinline__ void split8(const float v[8], bf16x8 &h, bf16x8 &l) {
    #pragma unroll
    for (int e = 0; e < 8; e++) {
        unsigned short hs = rne_bf16(v[e]);
        float hf = __builtin_bit_cast(float, ((unsigned)hs) << 16);
        h[e] = (short)hs;
        l[e] = (short)rne_bf16(v[e] - hf);
    }
}

// ---------- tables: champW1, roleW1 (grid 45x256 = 11520 = 170*64+10*64 exactly) ----------
__global__ void k_tables(const float* __restrict__ champ, const float* __restrict__ role,
                         const float* __restrict__ W1,
                         float* __restrict__ chW, float* __restrict__ roW) {
    int t = blockIdx.x * blockDim.x + threadIdx.x;
    if (t < 170 * 64) {
        int c = t >> 6, j = t & 63;
        float s = 0.f;
        #pragma unroll
        for (int k = 0; k < 32; k++) s += champ[c * 32 + k] * W1[k * 64 + j];
        chW[t] = s;
    } else if (t < 170 * 64 + 10 * 64) {
        int t2 = t - 170 * 64;
        int r = t2 >> 6, j = t2 & 63;
        float s = 0.f;
        #pragma unroll
        for (int k = 0; k < 8; k++) s += role[r * 8 + k] * W1[(32 + k) * 64 + j];
        roW[t2] = s;
    }
}

// ---------- pre-split W2 / fc1W into MFMA B-fragments (1 wave) ----------
// frag k-map (consumer identical): k = 32*ks + (e<4 ? 4q+e : 16+4q+(e-4)), q=lane>>4, c=lane&15
__global__ void k_frags(const float* __restrict__ W2, const float* __restrict__ fc1W,
                        bf16x8* __restrict__ w2f, bf16x8* __restrict__ f1f) {
    const int lane = threadIdx.x & 63, q = lane >> 4, c = lane & 15;
    #pragma unroll
    for (int ks = 0; ks < 2; ks++)
    #pragma unroll
    for (int t = 0; t < 4; t++) {
        float v[8];
        #pragma unroll
        for (int e = 0; e < 8; e++) {
            int k = 32 * ks + (e < 4 ? 4 * q + e : 16 + 4 * q + (e - 4));
            v[e] = W2[k * 64 + 16 * t + c];
        }
        bf16x8 h, l; split8(v, h, l);
        w2f[(ks * 4 + t) * 64 + lane] = h;
        w2f[(8 + ks * 4 + t) * 64 + lane] = l;
    }
    #pragma unroll
    for (int ks = 0; ks < 2; ks++)
    #pragma unroll
    for (int t = 0; t < 2; t++) {
        float v[8];
        #pragma unroll
        for (int e = 0; e < 8; e++) {
            int k = 32 * ks + (e < 4 ? 4 * q + e : 16 + 4 * q + (e - 4));
            v[e] = fc1W[k * 32 + 16 * t + c];
        }
        bf16x8 h, l; split8(v, h, l);
        f1f[(ks * 2 + t) * 64 + lane] = h;
        f1f[(4 + ks * 2 + t) * 64 + lane] = l;
    }
}

// ---------- bin edges: packed 4xu8 counts, transposed [word][graph] ----------
__global__ void k_edges(const int* __restrict__ ei, unsigned* __restrict__ cnt) {
    int stride = gridDim.x * blockDim.x;
    for (int e = blockIdx.x * blockDim.x + threadIdx.x; e < N_EDGES; e += stride) {
        unsigned s = (unsigned)ei[e];
        unsigned d = (unsigned)ei[N_EDGES + e];
        unsigned g = d / 10u;
        unsigned slot = (d % 10u) * 10u + (s % 10u);
        atomicAdd(&cnt[(slot >> 2) * N_GRAPHS + g], 1u << (8u * (slot & 3u)));
    }
}

// ---------- build normalized 10x12(padded) adjacency, thread per graph ----------
__global__ __launch_bounds__(256) void k_wmat(const unsigned* __restrict__ cnt,
                                              float* __restrict__ wmat) {
    int g = blockIdx.x * 256 + threadIdx.x;
    if (g >= N_GRAPHS) return;
    unsigned wv[25];
    #pragma unroll
    for (int i = 0; i < 25; i++) wv[i] = cnt[i * N_GRAPHS + g];   // coalesced
    float c100[100];
    #pragma unroll
    for (int s = 0; s < 100; s++)
        c100[s] = (float)((wv[s >> 2] >> (8 * (s & 3))) & 255u);
    float dinv[10];
    #pragma unroll
    for (int u = 0; u < 10; u++) {
        float s = 1.f;
        #pragma unroll
        for (int v = 0; v < 10; v++) s += c100[u * 10 + v];
        dinv[u] = rsqrtf(s);
    }
    float4* wp = (float4*)(wmat + (size_t)g * 120);   // 480B-aligned
    #pragma unroll
    for (int u = 0; u < 10; u++) {
        float row[12];
        #pragma unroll
        for (int v = 0; v < 10; v++)
            row[v] = (c100[u * 10 + v] + (u == v ? 1.f : 0.f)) * dinv[u] * dinv[v];
        row[10] = 0.f; row[11] = 0.f;
        #pragma unroll
        for (int r = 0; r < 3; r++)
            wp[u * 3 + r] = make_float4(row[4 * r], row[4 * r + 1], row[4 * r + 2], row[4 * r + 3]);
    }
}

// ---------- pass1: a1 = Wmat@hw + b1 via SGPR Wmat ; BN1 stats ----------
__global__ __launch_bounds__(256) void k_pass1(
    const int* __restrict__ x, const float* __restrict__ wmat,
    const float* __restrict__ chW, const float* __restrict__ roW,
    const float* __restrict__ W1, const float* __restrict__ b1,
    float* __restrict__ p1s, float* __restrict__ p1q)
{
    const int lane = threadIdx.x & 63;
    const int g = __builtin_amdgcn_readfirstlane(blockIdx.x * 4 + (threadIdx.x >> 6));
    const int* xg = x + g * 30;           // uniform -> s_load
    const float* wm = wmat + g * 120;     // uniform -> s_load

    const float w1t = W1[40 * 64 + lane];
    float hw[10];
    #pragma unroll
    for (int u = 0; u < 10; u++) {
        int cu = xg[u * 3 + 0];
        int ru = xg[u * 3 + 1];
        float tm = (float)xg[u * 3 + 2];
        hw[u] = chW[cu * 64 + lane] + roW[ru * 64 + lane] + tm * w1t;
    }
    const float b1v = b1[lane];
    float s = 0.f, ss = 0.f;
    #pragma unroll
    for (int u = 0; u < 10; u++) {
        float a = b1v;
        #pragma unroll
        for (int v = 0; v < 10; v++) a = fmaf(wm[u * 12 + v], hw[v], a);
        s += a; ss += a * a;
    }
    int slot = g & 127;
    atomicAdd(&p1s[slot * 64 + lane], s);
    atomicAdd(&p1q[slot * 64 + lane], ss);
}

// ---------- finalize BN1 (parallel: 1024 threads) ----------
__global__ __launch_bounds__(1024) void k_fin1(
    const float* __restrict__ p1s, const float* __restrict__ p1q,
    const float* __restrict__ gamma, const float* __restrict__ beta,
    float* __restrict__ sc)
{
    __shared__ double rs[16][64], rq[16][64];
    int s = threadIdx.x >> 6, j = threadIdx.x & 63;
    double a = 0.0, b = 0.0;
    for (int k = s; k < 128; k += 16) { a += p1s[k * 64 + j]; b += p1q[k * 64 + j]; }
    rs[s][j] = a; rq[s][j] = b;
    __syncthreads();
    if (s == 0) {
        for (int k = 1; k < 16; k++) { a += rs[k][j]; b += rq[k][j]; }
        double mu = a / (double)N_NODES;
        double var = b / (double)N_NODES - mu * mu;
        float scl = gamma[j] * rsqrtf((float)var + 1e-5f);
        sc[j] = scl;
        sc[64 + j] = beta[j] - (float)mu * scl;
    }
}

// ---------- main pass: 4 graphs/wave; conv1+BN+relu, conv2, a2 MFMA, pool -> G ----------
__global__ __launch_bounds__(256) void k_main(
    const int* __restrict__ x, const float* __restrict__ wmat,
    const float* __restrict__ chW, const float* __restrict__ roW,
    const float* __restrict__ W1, const float* __restrict__ b1,
    const float* __restrict__ sc,
    const bf16x8* __restrict__ w2f, const float* __restrict__ b2,
    float* __restrict__ G)
{
    __shared__ float stage[4][1088];   // per-wave u2 tile [16 rows][68], 17.4 KB

    const int w = threadIdx.x >> 6, lane = threadIdx.x & 63;
    const int q = lane >> 4, c = lane & 15;
    const int wid = __builtin_amdgcn_readfirstlane((int)blockIdx.x * 4 + w);

    float* up = stage[w];
    for (int i = lane; i < 408; i += 64) up[680 + i] = 0.f;   // zero pad rows 10..15

    const float w1t = W1[40 * 64 + lane];
    const float b1v = b1[lane];
    const float sc1 = sc[lane], sf1 = sc[64 + lane];
    float b2v[4];
    #pragma unroll
    for (int t = 0; t < 4; t++) b2v[t] = b2[16 * t + c];

    #pragma unroll 1
    for (int gi = 0; gi < 4; gi++) {
        const int g = wid * 4 + gi;
        const int* xg = x + g * 30;           // uniform -> s_load
        const float* wm = wmat + g * 120;     // uniform -> s_load

        float hw[10];
        #pragma unroll
        for (int u = 0; u < 10; u++) {
            int cu = xg[u * 3 + 0];
            int ru = xg[u * 3 + 1];
            float tm = (float)xg[u * 3 + 2];
            hw[u] = chW[cu * 64 + lane] + roW[ru * 64 + lane] + tm * w1t;
        }
        float h1[10];
        #pragma unroll
        for (int u = 0; u < 10; u++) {
            float a = b1v;
            #pragma unroll
            for (int v2 = 0; v2 < 10; v2++) a = fmaf(wm[u * 12 + v2], hw[v2], a);
            h1[u] = fmaxf(fmaf(a, sc1, sf1), 0.f);
        }
        #pragma unroll
        for (int u = 0; u < 10; u++) {
            float t = 0.f;
            #pragma unroll
            for (int v2 = 0; v2 < 10; v2++) t = fmaf(wm[u * 12 + v2], h1[v2], t);
            up[u * 68 + lane] = t;            // wave-private tile, no barrier needed
        }
        // a2 = u2 @ W2 via 3-product split MFMA (weights from global, L1-hot)
        f32x4 acc[4] = {f32x4{0.f,0.f,0.f,0.f}, f32x4{0.f,0.f,0.f,0.f},
                        f32x4{0.f,0.f,0.f,0.f}, f32x4{0.f,0.f,0.f,0.f}};
        const float4* rowp = (const float4*)(up + c * 68);
        #pragma unroll
        for (int ks = 0; ks < 2; ks++) {
            float4 A0 = rowp[8 * ks + q];
            float4 A1 = rowp[8 * ks + 4 + q];
            float av[8] = {A0.x, A0.y, A0.z, A0.w, A1.x, A1.y, A1.z, A1.w};
            bf16x8 ah, al; split8(av, ah, al);
            #pragma unroll
            for (int t = 0; t < 4; t++) {
                bf16x8 bh = w2f[(ks * 4 + t) * 64 + lane];
                bf16x8 bl = w2f[(8 + ks * 4 + t) * 64 + lane];
                acc[t] = __builtin_amdgcn_mfma_f32_16x16x32_bf16(ah, bh, acc[t], 0, 0, 0);
                acc[t] = __builtin_amdgcn_mfma_f32_16x16x32_bf16(al, bh, acc[t], 0, 0, 0);
                acc[t] = __builtin_amdgcn_mfma_f32_16x16x32_bf16(ah, bl, acc[t], 0, 0, 0);
            }
        }
        // relu + masked mean-pool; C rows are nodes m = 4q+r
        float pool[4];
        #pragma unroll
        for (int t = 0; t < 4; t++) {
            float pt = 0.f;
            #pragma unroll
            for (int r = 0; r < 4; r++) {
                int m = 4 * q + r;
                float val = fmaxf(acc[t][r] + b2v[t], 0.f);
                pt += (m < 10) ? val : 0.f;
            }
            pt += __shfl_xor(pt, 16);
            pt += __shfl_xor(pt, 32);
            pool[t] = pt * 0.1f;
        }
        // lane j holds pool for col j when t = j>>4 = q
        float gv = (q == 0) ? pool[0] : (q == 1) ? pool[1] : (q == 2) ? pool[2] : pool[3];
        G[(size_t)g * 64 + lane] = gv;        // coalesced 256B store
    }
}

// ---------- fc1 via MFMA over 16 pooled vectors per wave ; z + BN2 stats ----------
__global__ __launch_bounds__(256) void k_fc(
    const float* __restrict__ G, const bf16x8* __restrict__ f1f,
    const float* __restrict__ fc1b,
    float* __restrict__ zbuf, float* __restrict__ p2s, float* __restrict__ p2q)
{
    const int w = threadIdx.x >> 6, lane = threadIdx.x & 63;
    const int q = lane >> 4, c = lane & 15;
    const int wid = __builtin_amdgcn_readfirstlane((int)blockIdx.x * 4 + w);
    if (wid >= N_GRAPHS / 16) return;
    const int g0 = wid * 16;

    float f1bv[2];
    #pragma unroll
    for (int t = 0; t < 2; t++) f1bv[t] = fc1b[16 * t + c];

    f32x4 facc[2] = {f32x4{0.f,0.f,0.f,0.f}, f32x4{0.f,0.f,0.f,0.f}};
    const float* grow = G + (size_t)(g0 + c) * 64;
    #pragma unroll
    for (int ks = 0; ks < 2; ks++) {
        float4 G0 = *(const float4*)(grow + 32 * ks + 4 * q);
        float4 G1 = *(const float4*)(grow + 32 * ks + 16 + 4 * q);
        float gvv[8] = {G0.x, G0.y, G0.z, G0.w, G1.x, G1.y, G1.z, G1.w};
        bf16x8 gh, gl; split8(gvv, gh, gl);
        #pragma unroll
        for (int t = 0; t < 2; t++) {
            bf16x8 fh = f1f[(ks * 2 + t) * 64 + lane];
            bf16x8 fl = f1f[(4 + ks * 2 + t) * 64 + lane];
            facc[t] = __builtin_amdgcn_mfma_f32_16x16x32_bf16(gh, fh, facc[t], 0, 0, 0);
            facc[t] = __builtin_amdgcn_mfma_f32_16x16x32_bf16(gl, fh, facc[t], 0, 0, 0);
            facc[t] = __builtin_amdgcn_mfma_f32_16x16x32_bf16(gh, fl, facc[t], 0, 0, 0);
        }
    }
    // z + stats from C regs: row = graph 4q+r, col = 16t+c
    #pragma unroll
    for (int t = 0; t < 2; t++)
    #pragma unroll
    for (int r = 0; r < 4; r++) {
        int gg = g0 + 4 * q + r;
        float zv = facc[t][r] + f1bv[t];
        zbuf[gg * 32 + 16 * t + c] = zv;
        int slot = gg & 127;
        atomicAdd(&p2s[slot * 32 + 16 * t + c], zv);
        atomicAdd(&p2q[slot * 32 + 16 * t + c], zv * zv);
    }
}

// ---------- finalize BN2 (parallel: 512 threads) ----------
__global__ __launch_bounds__(512) void k_fin2(
    const float* __restrict__ p2s, const float* __restrict__ p2q,
    const float* __restrict__ gamma, const float* __restrict__ beta,
    float* __restrict__ sc)
{
    __shared__ double rs[16][32], rq[16][32];
    int s = threadIdx.x >> 5, j = threadIdx.x & 31;
    double a = 0.0, b = 0.0;
    for (int k = s; k < 128; k += 16) { a += p2s[k * 32 + j]; b += p2q[k * 32 + j]; }
    rs[s][j] = a; rq[s][j] = b;
    __syncthreads();
    if (s == 0) {
        for (int k = 1; k < 16; k++) { a += rs[k][j]; b += rq[k][j]; }
        double mu = a / (double)N_GRAPHS;
        double var = b / (double)N_GRAPHS - mu * mu;
        float scl = gamma[j] * rsqrtf((float)var + 1e-5f);
        sc[128 + j] = scl;
        sc[160 + j] = beta[j] - (float)mu * scl;
    }
}

// ---------- pass3: BN2 + relu + fc2 + sigmoid ----------
__global__ __launch_bounds__(256) void k_pass3(
    const float* __restrict__ z, const float* __restrict__ sc,
    const float* __restrict__ fc2W, const float* __restrict__ fc2b,
    float* __restrict__ out)
{
    int t = blockIdx.x * blockDim.x + threadIdx.x;
    int g = t >> 5, j = t & 31;
    float y = fmaxf(fmaf(z[g * 32 + j], sc[128 + j], sc[160 + j]), 0.f);
    float acc = y * fc2W[j];
    #pragma unroll
    for (int off = 16; off > 0; off >>= 1) acc += __shfl_xor(acc, off, 32);
    if (j == 0) out[g] = 1.0f / (1.0f + __expf(-(acc + fc2b[0])));
}

extern "C" void kernel_launch(void* const* d_in, const int* in_sizes, int n_in,
                              void* d_out, int out_size, void* d_ws, size_t ws_size,
                              hipStream_t stream) {
    const int*   x      = (const int*)d_in[0];
    const int*   ei     = (const int*)d_in[1];
    const float* champ  = (const float*)d_in[3];
    const float* role   = (const float*)d_in[4];
    const float* W1     = (const float*)d_in[5];
    const float* b1     = (const float*)d_in[6];
    const float* gamma1 = (const float*)d_in[7];
    const float* beta1  = (const float*)d_in[8];
    const float* W2     = (const float*)d_in[9];
    const float* b2     = (const float*)d_in[10];
    const float* fc1W   = (const float*)d_in[11];
    const float* fc1b   = (const float*)d_in[12];
    const float* gamma2 = (const float*)d_in[13];
    const float* beta2  = (const float*)d_in[14];
    const float* fc2W   = (const float*)d_in[15];
    const float* fc2b   = (const float*)d_in[16];
    float* out = (float*)d_out;

    char* ws = (char*)d_ws;
    unsigned* cnt  = (unsigned*)(ws + CNT_OFF);
    float* p1s  = (float*)(ws + P1S_OFF);
    float* p1q  = (float*)(ws + P1Q_OFF);
    float* p2s  = (float*)(ws + P2S_OFF);
    float* p2q  = (float*)(ws + P2Q_OFF);
    float* chW  = (float*)(ws + CHW_OFF);
    float* roW  = (float*)(ws + ROW_OFF);
    bf16x8* w2f = (bf16x8*)(ws + W2F_OFF);
    bf16x8* f1f = (bf16x8*)(ws + F1F_OFF);
    float* scb  = (float*)(ws + SC_OFF);
    float* zbuf = (float*)(ws + ZB_OFF);
    float* wmat = (float*)(ws + WM_OFF);
    float* G    = (float*)(ws + G_OFF);

    hipMemsetAsync(ws, 0, ZERO_BYTES, stream);
    k_tables<<<45, 256, 0, stream>>>(champ, role, W1, chW, roW);
    k_frags<<<1, 64, 0, stream>>>(W2, fc1W, w2f, f1f);
    k_edges<<<2048, 256, 0, stream>>>(ei, cnt);
    k_wmat<<<(N_GRAPHS + 255) / 256, 256, 0, stream>>>(cnt, wmat);
    k_pass1<<<N_GRAPHS / 4, 256, 0, stream>>>(x, wmat, chW, roW, W1, b1, p1s, p1q);
    k_fin1<<<1, 1024, 0, stream>>>(p1s, p1q, gamma1, beta1, scb);
    k_main<<<N_GRAPHS / 16, 256, 0, stream>>>(x, wmat, chW, roW, W1, b1, scb,
                                              w2f, b2, G);
    k_fc<<<(N_GRAPHS / 16 + 3) / 4, 256, 0, stream>>>(G, f1f, fc1b, zbuf, p2s, p2q);
    k_fin2<<<1, 512, 0, stream>>>(p2s, p2q, gamma2, beta2, scb);
    k_pass3<<<N_GRAPHS / 8, 256, 0, stream>>>(zbuf, scb, fc2W, fc2b, out);
}

// Round 7
// 400.978 us; speedup vs baseline: 1.5869x; 1.0244x over previous
//
#include <hip/hip_runtime.h>
#include <hip/hip_bf16.h>
#include <math.h>

typedef __attribute__((ext_vector_type(8))) short bf16x8;
typedef __attribute__((ext_vector_type(4))) float f32x4;

#define N_NODES   500000
#define N_GRAPHS  50000
#define N_EDGES   4000000
#define REP_WORDS 1250000u     // 25 words x 50000 graphs per replica

// ---- workspace layout (bytes) ----
// CNT region (40 MB) is dead after k_wmat; zbuf and G alias into it.
#define CNT_OFF   0u           // u32[8][25][50000] per-XCD packed 4xu8 counts
#define ZB_OFF    0u           // f32[50000*32] (alias, written by k_fc)
#define G_OFF     6400000u     // f32[50000*64] (alias, written by k_main)
#define P1S_OFF   40000000u    // f32[128*64]
#define P1Q_OFF   40032768u    // f32[128*64]
#define P2S_OFF   40065536u    // f32[128*32]
#define P2Q_OFF   40081920u    // f32[128*32]
#define ZERO_BYTES 40098304u   // memset covers cnt replicas + partial stats
#define CHW_OFF   40098304u    // f32[170*64]
#define ROW_OFF   40141824u    // f32[10*64]
#define W2F_OFF   40144384u    // bf16x8[16][64]
#define F1F_OFF   40160768u    // bf16x8[8][64]
#define SC_OFF    40168960u    // f32[192]
#define WM_OFF    40169728u    // f32[50000*100]   (ends 60,169,728)

// split 8 f32 into hi/lo bf16x8 via hw cvt (compiler emits v_cvt_pk_bf16_f32)
__device__ __forceinline__ void split8v(const float v[8], bf16x8 &h, bf16x8 &l) {
    #pragma unroll
    for (int e = 0; e < 8; e++) {
        __hip_bfloat16 hb = __float2bfloat16(v[e]);
        float hf = __bfloat162float(hb);
        __hip_bfloat16 lb = __float2bfloat16(v[e] - hf);
        h[e] = __builtin_bit_cast(short, hb);
        l[e] = __builtin_bit_cast(short, lb);
    }
}

// ---------- fused: tables (blocks 0..44) + MFMA weight frags (block 45) ----------
__global__ __launch_bounds__(256) void k_tabfrag(
    const float* __restrict__ champ, const float* __restrict__ role,
    const float* __restrict__ W1, const float* __restrict__ W2,
    const float* __restrict__ fc1W,
    float* __restrict__ chW, float* __restrict__ roW,
    bf16x8* __restrict__ w2f, bf16x8* __restrict__ f1f)
{
    if (blockIdx.x < 45) {
        int t = blockIdx.x * 256 + threadIdx.x;   // 11520 = 170*64 + 10*64 exactly
        if (t < 170 * 64) {
            int c = t >> 6, j = t & 63;
            float s = 0.f;
            #pragma unroll
            for (int k = 0; k < 32; k++) s += champ[c * 32 + k] * W1[k * 64 + j];
            chW[t] = s;
        } else {
            int t2 = t - 170 * 64;
            int r = t2 >> 6, j = t2 & 63;
            float s = 0.f;
            #pragma unroll
            for (int k = 0; k < 8; k++) s += role[r * 8 + k] * W1[(32 + k) * 64 + j];
            roW[t2] = s;
        }
    } else if (threadIdx.x < 64) {
        const int lane = threadIdx.x, q = lane >> 4, c = lane & 15;
        #pragma unroll
        for (int ks = 0; ks < 2; ks++)
        #pragma unroll
        for (int t = 0; t < 4; t++) {
            float v[8];
            #pragma unroll
            for (int e = 0; e < 8; e++) {
                int k = 32 * ks + (e < 4 ? 4 * q + e : 16 + 4 * q + (e - 4));
                v[e] = W2[k * 64 + 16 * t + c];
            }
            bf16x8 h, l; split8v(v, h, l);
            w2f[(ks * 4 + t) * 64 + lane] = h;
            w2f[(8 + ks * 4 + t) * 64 + lane] = l;
        }
        #pragma unroll
        for (int ks = 0; ks < 2; ks++)
        #pragma unroll
        for (int t = 0; t < 2; t++) {
            float v[8];
            #pragma unroll
            for (int e = 0; e < 8; e++) {
                int k = 32 * ks + (e < 4 ? 4 * q + e : 16 + 4 * q + (e - 4));
                v[e] = fc1W[k * 32 + 16 * t + c];
            }
            bf16x8 h, l; split8v(v, h, l);
            f1f[(ks * 2 + t) * 64 + lane] = h;
            f1f[(4 + ks * 2 + t) * 64 + lane] = l;
        }
    }
}

// ---------- bin edges: per-XCD replicated counts, XCD-L2-local atomics ----------
__global__ void k_edges(const int* __restrict__ ei, unsigned* __restrict__ cnt) {
    unsigned xcc;
    asm volatile("s_getreg_b32 %0, hwreg(20, 0, 32)" : "=s"(xcc));  // HW_REG_XCC_ID
    unsigned* base = cnt + (xcc & 7u) * REP_WORDS;
    const int4* s4 = (const int4*)ei;
    const int4* d4 = (const int4*)(ei + N_EDGES);
    int stride = gridDim.x * blockDim.x;
    for (int i = blockIdx.x * blockDim.x + threadIdx.x; i < N_EDGES / 4; i += stride) {
        int4 s = s4[i], d = d4[i];
        #pragma unroll
        for (int e = 0; e < 4; e++) {
            unsigned sv = (unsigned)(e == 0 ? s.x : e == 1 ? s.y : e == 2 ? s.z : s.w);
            unsigned dv = (unsigned)(e == 0 ? d.x : e == 1 ? d.y : e == 2 ? d.z : d.w);
            unsigned g = dv / 10u;
            unsigned slot = (dv % 10u) * 10u + (sv % 10u);
            __hip_atomic_fetch_add(&base[(slot >> 2) * N_GRAPHS + g],
                                   1u << (8u * (slot & 3u)),
                                   __ATOMIC_RELAXED, __HIP_MEMORY_SCOPE_WORKGROUP);
        }
    }
}

// ---------- sum replicas + build normalized 10x10 adjacency, thread per graph ----------
__global__ __launch_bounds__(256) void k_wmat(const unsigned* __restrict__ cnt,
                                              float* __restrict__ wmat) {
    int g = blockIdx.x * 256 + threadIdx.x;
    if (g >= N_GRAPHS) return;
    unsigned wv[25];
    #pragma unroll
    for (int i = 0; i < 25; i++) {
        unsigned s = 0;
        #pragma unroll
        for (int r = 0; r < 8; r++) s += cnt[r * REP_WORDS + i * 50000u + (unsigned)g];
        wv[i] = s;   // packed byte add: per-slot counts << 256, no carry
    }
    float c100[100];
    #pragma unroll
    for (int s = 0; s < 100; s++)
        c100[s] = (float)((wv[s >> 2] >> (8 * (s & 3))) & 255u);
    float dinv[10];
    #pragma unroll
    for (int u = 0; u < 10; u++) {
        float s = 1.f;
        #pragma unroll
        for (int v = 0; v < 10; v++) s += c100[u * 10 + v];
        dinv[u] = rsqrtf(s);
    }
    #pragma unroll
    for (int u = 0; u < 10; u++)
        #pragma unroll
        for (int v = 0; v < 10; v++)
            c100[u * 10 + v] = (c100[u * 10 + v] + (u == v ? 1.f : 0.f)) * dinv[u] * dinv[v];
    float4* wp = (float4*)(wmat + (size_t)g * 100);   // 400B stride: 16B aligned
    #pragma unroll
    for (int r = 0; r < 25; r++)
        wp[r] = make_float4(c100[4 * r], c100[4 * r + 1], c100[4 * r + 2], c100[4 * r + 3]);
}

// ---------- pass1: a1 = Wmat@hw + b1 via SGPR Wmat ; BN1 stats ----------
__global__ __launch_bounds__(256) void k_pass1(
    const int* __restrict__ x, const float* __restrict__ wmat,
    const float* __restrict__ chW, const float* __restrict__ roW,
    const float* __restrict__ W1, const float* __restrict__ b1,
    float* __restrict__ p1s, float* __restrict__ p1q)
{
    const int lane = threadIdx.x & 63;
    const int g = __builtin_amdgcn_readfirstlane(blockIdx.x * 4 + (threadIdx.x >> 6));
    const int* xg = x + g * 30;           // uniform -> s_load
    const float* wm = wmat + g * 100;     // uniform -> s_load

    const float w1t = W1[40 * 64 + lane];
    float hw[10];
    #pragma unroll
    for (int u = 0; u < 10; u++) {
        int cu = xg[u * 3 + 0];
        int ru = xg[u * 3 + 1];
        float tm = (float)xg[u * 3 + 2];
        hw[u] = chW[cu * 64 + lane] + roW[ru * 64 + lane] + tm * w1t;
    }
    const float b1v = b1[lane];
    float s = 0.f, ss = 0.f;
    #pragma unroll
    for (int u = 0; u < 10; u++) {
        float a = b1v;
        #pragma unroll
        for (int v = 0; v < 10; v++) a = fmaf(wm[u * 10 + v], hw[v], a);
        s += a; ss += a * a;
    }
    int slot = g & 127;
    atomicAdd(&p1s[slot * 64 + lane], s);
    atomicAdd(&p1q[slot * 64 + lane], ss);
}

// ---------- finalize BN1 (parallel) ----------
__global__ __launch_bounds__(1024) void k_fin1(
    const float* __restrict__ p1s, const float* __restrict__ p1q,
    const float* __restrict__ gamma, const float* __restrict__ beta,
    float* __restrict__ sc)
{
    __shared__ double rs[16][64], rq[16][64];
    int s = threadIdx.x >> 6, j = threadIdx.x & 63;
    double a = 0.0, b = 0.0;
    for (int k = s; k < 128; k += 16) { a += p1s[k * 64 + j]; b += p1q[k * 64 + j]; }
    rs[s][j] = a; rq[s][j] = b;
    __syncthreads();
    if (s == 0) {
        for (int k = 1; k < 16; k++) { a += rs[k][j]; b += rq[k][j]; }
        double mu = a / (double)N_NODES;
        double var = b / (double)N_NODES - mu * mu;
        float scl = gamma[j] * rsqrtf((float)var + 1e-5f);
        sc[j] = scl;
        sc[64 + j] = beta[j] - (float)mu * scl;
    }
}

// ---------- main pass: 4 graphs/wave; conv1+BN+relu, conv2, a2 MFMA, pool -> G ----------
__global__ __launch_bounds__(256) void k_main(
    const int* __restrict__ x, const float* __restrict__ wmat,
    const float* __restrict__ chW, const float* __restrict__ roW,
    const float* __restrict__ W1, const float* __restrict__ b1,
    const float* __restrict__ sc,
    const bf16x8* __restrict__ w2f, const float* __restrict__ b2,
    float* __restrict__ G)
{
    __shared__ float stage[4][1088];   // per-wave u2 tile [16 rows][68]

    const int w = threadIdx.x >> 6, lane = threadIdx.x & 63;
    const int q = lane >> 4, c = lane & 15;
    const int wid = __builtin_amdgcn_readfirstlane((int)blockIdx.x * 4 + w);

    float* up = stage[w];
    for (int i = lane; i < 408; i += 64) up[680 + i] = 0.f;   // zero pad rows 10..15

    const float w1t = W1[40 * 64 + lane];
    const float b1v = b1[lane];
    const float sc1 = sc[lane], sf1 = sc[64 + lane];
    float b2v[4];
    #pragma unroll
    for (int t = 0; t < 4; t++) b2v[t] = b2[16 * t + c];

    #pragma unroll 1
    for (int gi = 0; gi < 4; gi++) {
        const int g = wid * 4 + gi;
        const int* xg = x + g * 30;           // uniform -> s_load
        const float* wm = wmat + g * 100;     // uniform -> s_load

        float hw[10];
        #pragma unroll
        for (int u = 0; u < 10; u++) {
            int cu = xg[u * 3 + 0];
            int ru = xg[u * 3 + 1];
            float tm = (float)xg[u * 3 + 2];
            hw[u] = chW[cu * 64 + lane] + roW[ru * 64 + lane] + tm * w1t;
        }
        float h1[10];
        #pragma unroll
        for (int u = 0; u < 10; u++) {
            float a = b1v;
            #pragma unroll
            for (int v2 = 0; v2 < 10; v2++) a = fmaf(wm[u * 10 + v2], hw[v2], a);
            h1[u] = fmaxf(fmaf(a, sc1, sf1), 0.f);
        }
        #pragma unroll
        for (int u = 0; u < 10; u++) {
            float t = 0.f;
            #pragma unroll
            for (int v2 = 0; v2 < 10; v2++) t = fmaf(wm[u * 10 + v2], h1[v2], t);
            up[u * 68 + lane] = t;            // wave-private tile, no barrier
        }
        // a2 = u2 @ W2 via 3-product split MFMA (weights from global, L1-hot)
        f32x4 acc[4] = {f32x4{0.f,0.f,0.f,0.f}, f32x4{0.f,0.f,0.f,0.f},
                        f32x4{0.f,0.f,0.f,0.f}, f32x4{0.f,0.f,0.f,0.f}};
        const float4* rowp = (const float4*)(up + c * 68);
        #pragma unroll
        for (int ks = 0; ks < 2; ks++) {
            float4 A0 = rowp[8 * ks + q];
            float4 A1 = rowp[8 * ks + 4 + q];
            float av[8] = {A0.x, A0.y, A0.z, A0.w, A1.x, A1.y, A1.z, A1.w};
            bf16x8 ah, al; split8v(av, ah, al);
            #pragma unroll
            for (int t = 0; t < 4; t++) {
                bf16x8 bh = w2f[(ks * 4 + t) * 64 + lane];
                bf16x8 bl = w2f[(8 + ks * 4 + t) * 64 + lane];
                acc[t] = __builtin_amdgcn_mfma_f32_16x16x32_bf16(ah, bh, acc[t], 0, 0, 0);
                acc[t] = __builtin_amdgcn_mfma_f32_16x16x32_bf16(al, bh, acc[t], 0, 0, 0);
                acc[t] = __builtin_amdgcn_mfma_f32_16x16x32_bf16(ah, bl, acc[t], 0, 0, 0);
            }
        }
        // relu + masked mean-pool; C rows are nodes m = 4q+r
        float pool[4];
        #pragma unroll
        for (int t = 0; t < 4; t++) {
            float pt = 0.f;
            #pragma unroll
            for (int r = 0; r < 4; r++) {
                int m = 4 * q + r;
                float val = fmaxf(acc[t][r] + b2v[t], 0.f);
                pt += (m < 10) ? val : 0.f;
            }
            pt += __shfl_xor(pt, 16);
            pt += __shfl_xor(pt, 32);
            pool[t] = pt * 0.1f;
        }
        float gv = (q == 0) ? pool[0] : (q == 1) ? pool[1] : (q == 2) ? pool[2] : pool[3];
        G[(size_t)g * 64 + lane] = gv;        // coalesced 256B store
    }
}

// ---------- fc1 via MFMA over 16 pooled vectors per wave ; z + BN2 stats ----------
__global__ __launch_bounds__(256) void k_fc(
    const float* __restrict__ G, const bf16x8* __restrict__ f1f,
    const float* __restrict__ fc1b,
    float* __restrict__ zbuf, float* __restrict__ p2s, float* __restrict__ p2q)
{
    const int w = threadIdx.x >> 6, lane = threadIdx.x & 63;
    const int q = lane >> 4, c = lane & 15;
    const int wid = __builtin_amdgcn_readfirstlane((int)blockIdx.x * 4 + w);
    if (wid >= N_GRAPHS / 16) return;
    const int g0 = wid * 16;

    float f1bv[2];
    #pragma unroll
    for (int t = 0; t < 2; t++) f1bv[t] = fc1b[16 * t + c];

    f32x4 facc[2] = {f32x4{0.f,0.f,0.f,0.f}, f32x4{0.f,0.f,0.f,0.f}};
    const float* grow = G + (size_t)(g0 + c) * 64;
    #pragma unroll
    for (int ks = 0; ks < 2; ks++) {
        float4 G0 = *(const float4*)(grow + 32 * ks + 4 * q);
        float4 G1 = *(const float4*)(grow + 32 * ks + 16 + 4 * q);
        float gvv[8] = {G0.x, G0.y, G0.z, G0.w, G1.x, G1.y, G1.z, G1.w};
        bf16x8 gh, gl; split8v(gvv, gh, gl);
        #pragma unroll
        for (int t = 0; t < 2; t++) {
            bf16x8 fh = f1f[(ks * 2 + t) * 64 + lane];
            bf16x8 fl = f1f[(4 + ks * 2 + t) * 64 + lane];
            facc[t] = __builtin_amdgcn_mfma_f32_16x16x32_bf16(gh, fh, facc[t], 0, 0, 0);
            facc[t] = __builtin_amdgcn_mfma_f32_16x16x32_bf16(gl, fh, facc[t], 0, 0, 0);
            facc[t] = __builtin_amdgcn_mfma_f32_16x16x32_bf16(gh, fl, facc[t], 0, 0, 0);
        }
    }
    #pragma unroll
    for (int t = 0; t < 2; t++)
    #pragma unroll
    for (int r = 0; r < 4; r++) {
        int gg = g0 + 4 * q + r;
        float zv = facc[t][r] + f1bv[t];
        zbuf[gg * 32 + 16 * t + c] = zv;
        int slot = gg & 127;
        atomicAdd(&p2s[slot * 32 + 16 * t + c], zv);
        atomicAdd(&p2q[slot * 32 + 16 * t + c], zv * zv);
    }
}

// ---------- finalize BN2 (parallel) ----------
__global__ __launch_bounds__(512) void k_fin2(
    const float* __restrict__ p2s, const float* __restrict__ p2q,
    const float* __restrict__ gamma, const float* __restrict__ beta,
    float* __restrict__ sc)
{
    __shared__ double rs[16][32], rq[16][32];
    int s = threadIdx.x >> 5, j = threadIdx.x & 31;
    double a = 0.0, b = 0.0;
    for (int k = s; k < 128; k += 16) { a += p2s[k * 32 + j]; b += p2q[k * 32 + j]; }
    rs[s][j] = a; rq[s][j] = b;
    __syncthreads();
    if (s == 0) {
        for (int k = 1; k < 16; k++) { a += rs[k][j]; b += rq[k][j]; }
        double mu = a / (double)N_GRAPHS;
        double var = b / (double)N_GRAPHS - mu * mu;
        float scl = gamma[j] * rsqrtf((float)var + 1e-5f);
        sc[128 + j] = scl;
        sc[160 + j] = beta[j] - (float)mu * scl;
    }
}

// ---------- pass3: BN2 + relu + fc2 + sigmoid ----------
__global__ __launch_bounds__(256) void k_pass3(
    const float* __restrict__ z, const float* __restrict__ sc,
    const float* __restrict__ fc2W, const float* __restrict__ fc2b,
    float* __restrict__ out)
{
    int t = blockIdx.x * blockDim.x + threadIdx.x;
    int g = t >> 5, j = t & 31;
    float y = fmaxf(fmaf(z[g * 32 + j], sc[128 + j], sc[160 + j]), 0.f);
    float acc = y * fc2W[j];
    #pragma unroll
    for (int off = 16; off > 0; off >>= 1) acc += __shfl_xor(acc, off, 32);
    if (j == 0) out[g] = 1.0f / (1.0f + __expf(-(acc + fc2b[0])));
}

extern "C" void kernel_launch(void* const* d_in, const int* in_sizes, int n_in,
                              void* d_out, int out_size, void* d_ws, size_t ws_size,
                              hipStream_t stream) {
    const int*   x      = (const int*)d_in[0];
    const int*   ei     = (const int*)d_in[1];
    const float* champ  = (const float*)d_in[3];
    const float* role   = (const float*)d_in[4];
    const float* W1     = (const float*)d_in[5];
    const float* b1     = (const float*)d_in[6];
    const float* gamma1 = (const float*)d_in[7];
    const float* beta1  = (const float*)d_in[8];
    const float* W2     = (const float*)d_in[9];
    const float* b2     = (const float*)d_in[10];
    const float* fc1W   = (const float*)d_in[11];
    const float* fc1b   = (const float*)d_in[12];
    const float* gamma2 = (const float*)d_in[13];
    const float* beta2  = (const float*)d_in[14];
    const float* fc2W   = (const float*)d_in[15];
    const float* fc2b   = (const float*)d_in[16];
    float* out = (float*)d_out;

    char* ws = (char*)d_ws;
    unsigned* cnt  = (unsigned*)(ws + CNT_OFF);
    float* zbuf = (float*)(ws + ZB_OFF);
    float* G    = (float*)(ws + G_OFF);
    float* p1s  = (float*)(ws + P1S_OFF);
    float* p1q  = (float*)(ws + P1Q_OFF);
    float* p2s  = (float*)(ws + P2S_OFF);
    float* p2q  = (float*)(ws + P2Q_OFF);
    float* chW  = (float*)(ws + CHW_OFF);
    float* roW  = (float*)(ws + ROW_OFF);
    bf16x8* w2f = (bf16x8*)(ws + W2F_OFF);
    bf16x8* f1f = (bf16x8*)(ws + F1F_OFF);
    float* scb  = (float*)(ws + SC_OFF);
    float* wmat = (float*)(ws + WM_OFF);

    hipMemsetAsync(ws, 0, ZERO_BYTES, stream);
    k_tabfrag<<<46, 256, 0, stream>>>(champ, role, W1, W2, fc1W, chW, roW, w2f, f1f);
    k_edges<<<2048, 256, 0, stream>>>(ei, cnt);
    k_wmat<<<(N_GRAPHS + 255) / 256, 256, 0, stream>>>(cnt, wmat);
    k_pass1<<<N_GRAPHS / 4, 256, 0, stream>>>(x, wmat, chW, roW, W1, b1, p1s, p1q);
    k_fin1<<<1, 1024, 0, stream>>>(p1s, p1q, gamma1, beta1, scb);
    k_main<<<N_GRAPHS / 16, 256, 0, stream>>>(x, wmat, chW, roW, W1, b1, scb,
                                              w2f, b2, G);
    k_fc<<<(N_GRAPHS / 16 + 3) / 4, 256, 0, stream>>>(G, f1f, fc1b, zbuf, p2s, p2q);
    k_fin2<<<1, 512, 0, stream>>>(p2s, p2q, gamma2, beta2, scb);
    k_pass3<<<N_GRAPHS / 8, 256, 0, stream>>>(zbuf, scb, fc2W, fc2b, out);
}

// Round 8
// 325.874 us; speedup vs baseline: 1.9526x; 1.2305x over previous
//
#include <hip/hip_runtime.h>
#include <hip/hip_bf16.h>
#include <math.h>

typedef __attribute__((ext_vector_type(8))) short bf16x8;
typedef __attribute__((ext_vector_type(4))) float f32x4;

#define N_NODES   500000
#define N_GRAPHS  50000
#define N_EDGES   4000000
#define NPB   4000          // edges per k_part block (1000 blocks exactly)
#define NB    391           // buckets = ceil(50000/128)
#define BCAP  12288         // record capacity per bucket (mean 10240 + 20 sigma)

// ---- workspace layout (bytes) ----
// REC region (19.2 MB) is dead after k_count; zbuf and G alias into it.
#define REC_OFF   0u            // u32[391*12288] bucketed edge records
#define ZB_OFF    0u            // f32[50000*32] (alias, written by k_fc)
#define G_OFF     6400000u      // f32[50000*64] (alias, written by k_main)
#define TAIL_OFF  19218432u     // u32[391] bucket fill counts
#define P1S_OFF   19220000u     // f32[128*64]
#define P1Q_OFF   19252768u     // f32[128*64]
#define P2S_OFF   19285536u     // f32[128*32]
#define P2Q_OFF   19301920u     // f32[128*32]  (ends 19,318,304)
#define ZERO_LEN  99872u        // zero tail + all partial stats
#define CHW_OFF   19318304u     // f32[170*64]
#define ROW_OFF   19361824u     // f32[10*64]
#define W2F_OFF   19364384u     // bf16x8[16][64]
#define F1F_OFF   19380768u     // bf16x8[8][64]
#define SC_OFF    19388960u     // f32[192]
#define WM_OFF    19389728u     // f32[50000*100]  (ends 39,389,728)

// split 8 f32 into hi/lo bf16x8 via hw cvt
__device__ __forceinline__ void split8v(const float v[8], bf16x8 &h, bf16x8 &l) {
    #pragma unroll
    for (int e = 0; e < 8; e++) {
        __hip_bfloat16 hb = __float2bfloat16(v[e]);
        float hf = __bfloat162float(hb);
        __hip_bfloat16 lb = __float2bfloat16(v[e] - hf);
        h[e] = __builtin_bit_cast(short, hb);
        l[e] = __builtin_bit_cast(short, lb);
    }
}

// ---------- fused: tables (blocks 0..44) + MFMA weight frags (block 45) ----------
__global__ __launch_bounds__(256) void k_tabfrag(
    const float* __restrict__ champ, const float* __restrict__ role,
    const float* __restrict__ W1, const float* __restrict__ W2,
    const float* __restrict__ fc1W,
    float* __restrict__ chW, float* __restrict__ roW,
    bf16x8* __restrict__ w2f, bf16x8* __restrict__ f1f)
{
    if (blockIdx.x < 45) {
        int t = blockIdx.x * 256 + threadIdx.x;   // 11520 = 170*64 + 10*64 exactly
        if (t < 170 * 64) {
            int c = t >> 6, j = t & 63;
            float s = 0.f;
            #pragma unroll
            for (int k = 0; k < 32; k++) s += champ[c * 32 + k] * W1[k * 64 + j];
            chW[t] = s;
        } else {
            int t2 = t - 170 * 64;
            int r = t2 >> 6, j = t2 & 63;
            float s = 0.f;
            #pragma unroll
            for (int k = 0; k < 8; k++) s += role[r * 8 + k] * W1[(32 + k) * 64 + j];
            roW[t2] = s;
        }
    } else if (threadIdx.x < 64) {
        const int lane = threadIdx.x, q = lane >> 4, c = lane & 15;
        #pragma unroll
        for (int ks = 0; ks < 2; ks++)
        #pragma unroll
        for (int t = 0; t < 4; t++) {
            float v[8];
            #pragma unroll
            for (int e = 0; e < 8; e++) {
                int k = 32 * ks + (e < 4 ? 4 * q + e : 16 + 4 * q + (e - 4));
                v[e] = W2[k * 64 + 16 * t + c];
            }
            bf16x8 h, l; split8v(v, h, l);
            w2f[(ks * 4 + t) * 64 + lane] = h;
            w2f[(8 + ks * 4 + t) * 64 + lane] = l;
        }
        #pragma unroll
        for (int ks = 0; ks < 2; ks++)
        #pragma unroll
        for (int t = 0; t < 2; t++) {
            float v[8];
            #pragma unroll
            for (int e = 0; e < 8; e++) {
                int k = 32 * ks + (e < 4 ? 4 * q + e : 16 + 4 * q + (e - 4));
                v[e] = fc1W[k * 32 + 16 * t + c];
            }
            bf16x8 h, l; split8v(v, h, l);
            f1f[(ks * 2 + t) * 64 + lane] = h;
            f1f[(4 + ks * 2 + t) * 64 + lane] = l;
        }
    }
}

// ---------- phase A: partition edges into 391 graph-range buckets ----------
// No scattered global atomics: per-block LDS histogram, ONE hot fetch_add per
// (block,bucket), then in-order scatter (within-block sequential per bucket).
__global__ __launch_bounds__(256) void k_part(const int* __restrict__ ei,
                                              unsigned* __restrict__ rec,
                                              unsigned* __restrict__ tail) {
    __shared__ unsigned lcnt[NB];
    __shared__ unsigned gbase[NB];
    const int tid = threadIdx.x;
    const int e0 = blockIdx.x * NPB;

    for (int i = tid; i < NB; i += 256) lcnt[i] = 0;
    __syncthreads();
    // pass 1: bucket histogram (bucket = dst/1280 == (dst/10)>>7)
    for (int i = tid; i < NPB; i += 256) {
        unsigned d = (unsigned)ei[N_EDGES + e0 + i];
        atomicAdd(&lcnt[d / 1280u], 1u);
    }
    __syncthreads();
    for (int b = tid; b < NB; b += 256) {
        unsigned c = lcnt[b];
        gbase[b] = (unsigned)b * BCAP + (c ? atomicAdd(&tail[b], c) : 0u);
    }
    __syncthreads();
    for (int i = tid; i < NB; i += 256) lcnt[i] = 0;   // reuse as cursor
    __syncthreads();
    // pass 2: scatter keys (chunk is L2-hot from pass 1)
    for (int i = tid; i < NPB; i += 256) {
        unsigned s = (unsigned)ei[e0 + i];
        unsigned d = (unsigned)ei[N_EDGES + e0 + i];
        unsigned g = d / 10u;
        unsigned key = g * 100u + (d - g * 10u) * 10u + (s % 10u);
        unsigned b = g >> 7;
        unsigned pos = gbase[b] + atomicAdd(&lcnt[b], 1u);
        rec[pos] = key;
    }
}

// ---------- phase B: count in LDS + build normalized adjacency -> wmat ----------
__global__ __launch_bounds__(256) void k_count(const unsigned* __restrict__ rec,
                                               const unsigned* __restrict__ tail,
                                               float* __restrict__ wmat) {
    __shared__ unsigned cw[128 * 25];   // packed 4xu8 counts for 128 graphs
    const int tid = threadIdx.x;
    const unsigned b = blockIdx.x;

    for (int i = tid; i < 3200; i += 256) cw[i] = 0;
    __syncthreads();
    const unsigned n = tail[b];
    const unsigned base = b * BCAP;
    for (unsigned i = tid; i < n; i += 256) {
        unsigned key = rec[base + i];
        unsigned g = key / 100u;
        unsigned slot = key - g * 100u;
        atomicAdd(&cw[(g & 127u) * 25u + (slot >> 2)], 1u << (8u * (slot & 3u)));
    }
    __syncthreads();
    if (tid < 128) {
        unsigned g = b * 128u + (unsigned)tid;
        if (g < N_GRAPHS) {
            float c100[100];
            #pragma unroll
            for (int i = 0; i < 25; i++) {
                unsigned w = cw[tid * 25 + i];
                c100[4 * i + 0] = (float)(w & 255u);
                c100[4 * i + 1] = (float)((w >> 8) & 255u);
                c100[4 * i + 2] = (float)((w >> 16) & 255u);
                c100[4 * i + 3] = (float)(w >> 24);
            }
            float dinv[10];
            #pragma unroll
            for (int u = 0; u < 10; u++) {
                float s = 1.f;
                #pragma unroll
                for (int v = 0; v < 10; v++) s += c100[u * 10 + v];
                dinv[u] = rsqrtf(s);
            }
            #pragma unroll
            for (int u = 0; u < 10; u++)
                #pragma unroll
                for (int v = 0; v < 10; v++)
                    c100[u * 10 + v] = (c100[u * 10 + v] + (u == v ? 1.f : 0.f)) * dinv[u] * dinv[v];
            float4* wp = (float4*)(wmat + (size_t)g * 100);
            #pragma unroll
            for (int r = 0; r < 25; r++)
                wp[r] = make_float4(c100[4 * r], c100[4 * r + 1], c100[4 * r + 2], c100[4 * r + 3]);
        }
    }
}

// ---------- pass1: a1 = Wmat@hw + b1 via SGPR Wmat ; BN1 stats ----------
__global__ __launch_bounds__(256) void k_pass1(
    const int* __restrict__ x, const float* __restrict__ wmat,
    const float* __restrict__ chW, const float* __restrict__ roW,
    const float* __restrict__ W1, const float* __restrict__ b1,
    float* __restrict__ p1s, float* __restrict__ p1q)
{
    const int lane = threadIdx.x & 63;
    const int g = __builtin_amdgcn_readfirstlane(blockIdx.x * 4 + (threadIdx.x >> 6));
    const int* xg = x + g * 30;           // uniform -> s_load
    const float* wm = wmat + g * 100;     // uniform -> s_load

    const float w1t = W1[40 * 64 + lane];
    float hw[10];
    #pragma unroll
    for (int u = 0; u < 10; u++) {
        int cu = xg[u * 3 + 0];
        int ru = xg[u * 3 + 1];
        float tm = (float)xg[u * 3 + 2];
        hw[u] = chW[cu * 64 + lane] + roW[ru * 64 + lane] + tm * w1t;
    }
    const float b1v = b1[lane];
    float s = 0.f, ss = 0.f;
    #pragma unroll
    for (int u = 0; u < 10; u++) {
        float a = b1v;
        #pragma unroll
        for (int v = 0; v < 10; v++) a = fmaf(wm[u * 10 + v], hw[v], a);
        s += a; ss += a * a;
    }
    int slot = g & 127;
    atomicAdd(&p1s[slot * 64 + lane], s);
    atomicAdd(&p1q[slot * 64 + lane], ss);
}

// ---------- finalize BN1 (parallel) ----------
__global__ __launch_bounds__(1024) void k_fin1(
    const float* __restrict__ p1s, const float* __restrict__ p1q,
    const float* __restrict__ gamma, const float* __restrict__ beta,
    float* __restrict__ sc)
{
    __shared__ double rs[16][64], rq[16][64];
    int s = threadIdx.x >> 6, j = threadIdx.x & 63;
    double a = 0.0, b = 0.0;
    for (int k = s; k < 128; k += 16) { a += p1s[k * 64 + j]; b += p1q[k * 64 + j]; }
    rs[s][j] = a; rq[s][j] = b;
    __syncthreads();
    if (s == 0) {
        for (int k = 1; k < 16; k++) { a += rs[k][j]; b += rq[k][j]; }
        double mu = a / (double)N_NODES;
        double var = b / (double)N_NODES - mu * mu;
        float scl = gamma[j] * rsqrtf((float)var + 1e-5f);
        sc[j] = scl;
        sc[64 + j] = beta[j] - (float)mu * scl;
    }
}

// ---------- main pass: 4 graphs/wave; conv1+BN+relu, conv2, a2 MFMA, pool -> G ----------
__global__ __launch_bounds__(256) void k_main(
    const int* __restrict__ x, const float* __restrict__ wmat,
    const float* __restrict__ chW, const float* __restrict__ roW,
    const float* __restrict__ W1, const float* __restrict__ b1,
    const float* __restrict__ sc,
    const bf16x8* __restrict__ w2f, const float* __restrict__ b2,
    float* __restrict__ G)
{
    __shared__ float stage[4][1088];   // per-wave u2 tile [16 rows][68]

    const int w = threadIdx.x >> 6, lane = threadIdx.x & 63;
    const int q = lane >> 4, c = lane & 15;
    const int wid = __builtin_amdgcn_readfirstlane((int)blockIdx.x * 4 + w);

    float* up = stage[w];
    for (int i = lane; i < 408; i += 64) up[680 + i] = 0.f;   // zero pad rows 10..15

    const float w1t = W1[40 * 64 + lane];
    const float b1v = b1[lane];
    const float sc1 = sc[lane], sf1 = sc[64 + lane];
    float b2v[4];
    #pragma unroll
    for (int t = 0; t < 4; t++) b2v[t] = b2[16 * t + c];

    #pragma unroll 1
    for (int gi = 0; gi < 4; gi++) {
        const int g = wid * 4 + gi;
        const int* xg = x + g * 30;           // uniform -> s_load
        const float* wm = wmat + g * 100;     // uniform -> s_load

        float hw[10];
        #pragma unroll
        for (int u = 0; u < 10; u++) {
            int cu = xg[u * 3 + 0];
            int ru = xg[u * 3 + 1];
            float tm = (float)xg[u * 3 + 2];
            hw[u] = chW[cu * 64 + lane] + roW[ru * 64 + lane] + tm * w1t;
        }
        float h1[10];
        #pragma unroll
        for (int u = 0; u < 10; u++) {
            float a = b1v;
            #pragma unroll
            for (int v2 = 0; v2 < 10; v2++) a = fmaf(wm[u * 10 + v2], hw[v2], a);
            h1[u] = fmaxf(fmaf(a, sc1, sf1), 0.f);
        }
        #pragma unroll
        for (int u = 0; u < 10; u++) {
            float t = 0.f;
            #pragma unroll
            for (int v2 = 0; v2 < 10; v2++) t = fmaf(wm[u * 10 + v2], h1[v2], t);
            up[u * 68 + lane] = t;            // wave-private tile, no barrier
        }
        // a2 = u2 @ W2 via 3-product split MFMA (weights from global, L1-hot)
        f32x4 acc[4] = {f32x4{0.f,0.f,0.f,0.f}, f32x4{0.f,0.f,0.f,0.f},
                        f32x4{0.f,0.f,0.f,0.f}, f32x4{0.f,0.f,0.f,0.f}};
        const float4* rowp = (const float4*)(up + c * 68);
        #pragma unroll
        for (int ks = 0; ks < 2; ks++) {
            float4 A0 = rowp[8 * ks + q];
            float4 A1 = rowp[8 * ks + 4 + q];
            float av[8] = {A0.x, A0.y, A0.z, A0.w, A1.x, A1.y, A1.z, A1.w};
            bf16x8 ah, al; split8v(av, ah, al);
            #pragma unroll
            for (int t = 0; t < 4; t++) {
                bf16x8 bh = w2f[(ks * 4 + t) * 64 + lane];
                bf16x8 bl = w2f[(8 + ks * 4 + t) * 64 + lane];
                acc[t] = __builtin_amdgcn_mfma_f32_16x16x32_bf16(ah, bh, acc[t], 0, 0, 0);
                acc[t] = __builtin_amdgcn_mfma_f32_16x16x32_bf16(al, bh, acc[t], 0, 0, 0);
                acc[t] = __builtin_amdgcn_mfma_f32_16x16x32_bf16(ah, bl, acc[t], 0, 0, 0);
            }
        }
        // relu + masked mean-pool; C rows are nodes m = 4q+r
        float pool[4];
        #pragma unroll
        for (int t = 0; t < 4; t++) {
            float pt = 0.f;
            #pragma unroll
            for (int r = 0; r < 4; r++) {
                int m = 4 * q + r;
                float val = fmaxf(acc[t][r] + b2v[t], 0.f);
                pt += (m < 10) ? val : 0.f;
            }
            pt += __shfl_xor(pt, 16);
            pt += __shfl_xor(pt, 32);
            pool[t] = pt * 0.1f;
        }
        float gv = (q == 0) ? pool[0] : (q == 1) ? pool[1] : (q == 2) ? pool[2] : pool[3];
        G[(size_t)g * 64 + lane] = gv;        // coalesced 256B store
    }
}

// ---------- fc1 via MFMA over 16 pooled vectors per wave ; z + BN2 stats ----------
__global__ __launch_bounds__(256) void k_fc(
    const float* __restrict__ G, const bf16x8* __restrict__ f1f,
    const float* __restrict__ fc1b,
    float* __restrict__ zbuf, float* __restrict__ p2s, float* __restrict__ p2q)
{
    const int w = threadIdx.x >> 6, lane = threadIdx.x & 63;
    const int q = lane >> 4, c = lane & 15;
    const int wid = __builtin_amdgcn_readfirstlane((int)blockIdx.x * 4 + w);
    if (wid >= N_GRAPHS / 16) return;
    const int g0 = wid * 16;

    float f1bv[2];
    #pragma unroll
    for (int t = 0; t < 2; t++) f1bv[t] = fc1b[16 * t + c];

    f32x4 facc[2] = {f32x4{0.f,0.f,0.f,0.f}, f32x4{0.f,0.f,0.f,0.f}};
    const float* grow = G + (size_t)(g0 + c) * 64;
    #pragma unroll
    for (int ks = 0; ks < 2; ks++) {
        float4 G0 = *(const float4*)(grow + 32 * ks + 4 * q);
        float4 G1 = *(const float4*)(grow + 32 * ks + 16 + 4 * q);
        float gvv[8] = {G0.x, G0.y, G0.z, G0.w, G1.x, G1.y, G1.z, G1.w};
        bf16x8 gh, gl; split8v(gvv, gh, gl);
        #pragma unroll
        for (int t = 0; t < 2; t++) {
            bf16x8 fh = f1f[(ks * 2 + t) * 64 + lane];
            bf16x8 fl = f1f[(4 + ks * 2 + t) * 64 + lane];
            facc[t] = __builtin_amdgcn_mfma_f32_16x16x32_bf16(gh, fh, facc[t], 0, 0, 0);
            facc[t] = __builtin_amdgcn_mfma_f32_16x16x32_bf16(gl, fh, facc[t], 0, 0, 0);
            facc[t] = __builtin_amdgcn_mfma_f32_16x16x32_bf16(gh, fl, facc[t], 0, 0, 0);
        }
    }
    #pragma unroll
    for (int t = 0; t < 2; t++)
    #pragma unroll
    for (int r = 0; r < 4; r++) {
        int gg = g0 + 4 * q + r;
        float zv = facc[t][r] + f1bv[t];
        zbuf[gg * 32 + 16 * t + c] = zv;
        int slot = gg & 127;
        atomicAdd(&p2s[slot * 32 + 16 * t + c], zv);
        atomicAdd(&p2q[slot * 32 + 16 * t + c], zv * zv);
    }
}

// ---------- finalize BN2 (parallel) ----------
__global__ __launch_bounds__(512) void k_fin2(
    const float* __restrict__ p2s, const float* __restrict__ p2q,
    const float* __restrict__ gamma, const float* __restrict__ beta,
    float* __restrict__ sc)
{
    __shared__ double rs[16][32], rq[16][32];
    int s = threadIdx.x >> 5, j = threadIdx.x & 31;
    double a = 0.0, b = 0.0;
    for (int k = s; k < 128; k += 16) { a += p2s[k * 32 + j]; b += p2q[k * 32 + j]; }
    rs[s][j] = a; rq[s][j] = b;
    __syncthreads();
    if (s == 0) {
        for (int k = 1; k < 16; k++) { a += rs[k][j]; b += rq[k][j]; }
        double mu = a / (double)N_GRAPHS;
        double var = b / (double)N_GRAPHS - mu * mu;
        float scl = gamma[j] * rsqrtf((float)var + 1e-5f);
        sc[128 + j] = scl;
        sc[160 + j] = beta[j] - (float)mu * scl;
    }
}

// ---------- pass3: BN2 + relu + fc2 + sigmoid ----------
__global__ __launch_bounds__(256) void k_pass3(
    const float* __restrict__ z, const float* __restrict__ sc,
    const float* __restrict__ fc2W, const float* __restrict__ fc2b,
    float* __restrict__ out)
{
    int t = blockIdx.x * blockDim.x + threadIdx.x;
    int g = t >> 5, j = t & 31;
    float y = fmaxf(fmaf(z[g * 32 + j], sc[128 + j], sc[160 + j]), 0.f);
    float acc = y * fc2W[j];
    #pragma unroll
    for (int off = 16; off > 0; off >>= 1) acc += __shfl_xor(acc, off, 32);
    if (j == 0) out[g] = 1.0f / (1.0f + __expf(-(acc + fc2b[0])));
}

extern "C" void kernel_launch(void* const* d_in, const int* in_sizes, int n_in,
                              void* d_out, int out_size, void* d_ws, size_t ws_size,
                              hipStream_t stream) {
    const int*   x      = (const int*)d_in[0];
    const int*   ei     = (const int*)d_in[1];
    const float* champ  = (const float*)d_in[3];
    const float* role   = (const float*)d_in[4];
    const float* W1     = (const float*)d_in[5];
    const float* b1     = (const float*)d_in[6];
    const float* gamma1 = (const float*)d_in[7];
    const float* beta1  = (const float*)d_in[8];
    const float* W2     = (const float*)d_in[9];
    const float* b2     = (const float*)d_in[10];
    const float* fc1W   = (const float*)d_in[11];
    const float* fc1b   = (const float*)d_in[12];
    const float* gamma2 = (const float*)d_in[13];
    const float* beta2  = (const float*)d_in[14];
    const float* fc2W   = (const float*)d_in[15];
    const float* fc2b   = (const float*)d_in[16];
    float* out = (float*)d_out;

    char* ws = (char*)d_ws;
    unsigned* rec  = (unsigned*)(ws + REC_OFF);
    unsigned* tail = (unsigned*)(ws + TAIL_OFF);
    float* zbuf = (float*)(ws + ZB_OFF);
    float* G    = (float*)(ws + G_OFF);
    float* p1s  = (float*)(ws + P1S_OFF);
    float* p1q  = (float*)(ws + P1Q_OFF);
    float* p2s  = (float*)(ws + P2S_OFF);
    float* p2q  = (float*)(ws + P2Q_OFF);
    float* chW  = (float*)(ws + CHW_OFF);
    float* roW  = (float*)(ws + ROW_OFF);
    bf16x8* w2f = (bf16x8*)(ws + W2F_OFF);
    bf16x8* f1f = (bf16x8*)(ws + F1F_OFF);
    float* scb  = (float*)(ws + SC_OFF);
    float* wmat = (float*)(ws + WM_OFF);

    hipMemsetAsync(ws + TAIL_OFF, 0, ZERO_LEN, stream);
    k_tabfrag<<<46, 256, 0, stream>>>(champ, role, W1, W2, fc1W, chW, roW, w2f, f1f);
    k_part<<<N_EDGES / NPB, 256, 0, stream>>>(ei, rec, tail);
    k_count<<<NB, 256, 0, stream>>>(rec, tail, wmat);
    k_pass1<<<N_GRAPHS / 4, 256, 0, stream>>>(x, wmat, chW, roW, W1, b1, p1s, p1q);
    k_fin1<<<1, 1024, 0, stream>>>(p1s, p1q, gamma1, beta1, scb);
    k_main<<<N_GRAPHS / 16, 256, 0, stream>>>(x, wmat, chW, roW, W1, b1, scb,
                                              w2f, b2, G);
    k_fc<<<(N_GRAPHS / 16 + 3) / 4, 256, 0, stream>>>(G, f1f, fc1b, zbuf, p2s, p2q);
    k_fin2<<<1, 512, 0, stream>>>(p2s, p2q, gamma2, beta2, scb);
    k_pass3<<<N_GRAPHS / 8, 256, 0, stream>>>(zbuf, scb, fc2W, fc2b, out);
}

// Round 9
// 292.988 us; speedup vs baseline: 2.1718x; 1.1122x over previous
//
#include <hip/hip_runtime.h>
#include <hip/hip_bf16.h>
#include <math.h>

typedef __attribute__((ext_vector_type(8))) short bf16x8;
typedef __attribute__((ext_vector_type(4))) float f32x4;

#define N_NODES   500000
#define N_GRAPHS  50000
#define N_EDGES   4000000
#define NPB   16384         // edges per k_part block (245 blocks)
#define NPART ((N_EDGES + NPB - 1) / NPB)
#define NB    391           // buckets = ceil(50000/128)
#define BCAP  12288         // record capacity per bucket (mean 10240 + 20 sigma)

// ---- workspace layout (bytes) ----
// REC region (19.2 MB) is dead after k_count; zbuf and G alias into it.
#define REC_OFF   0u            // u32[391*12288] bucketed edge records
#define ZB_OFF    0u            // f32[50000*32] (alias, written by k_fc)
#define G_OFF     6400000u      // f32[50000*64] (alias, written by k_main)
#define TAIL_OFF  19218432u     // u32[391] bucket fill counts
#define P1S_OFF   19220000u     // f32[128*64]
#define P1Q_OFF   19252768u     // f32[128*64]
#define P2S_OFF   19285536u     // f32[128*32]
#define P2Q_OFF   19301920u     // f32[128*32]  (ends 19,318,304)
#define ZERO_LEN  99872u        // zero tail + all partial stats
#define CHW_OFF   19318304u     // f32[170*64]
#define ROW_OFF   19361824u     // f32[10*64]
#define W2F_OFF   19364384u     // bf16x8[16][64]
#define F1F_OFF   19380768u     // bf16x8[8][64]
#define SC_OFF    19388960u     // f32[192]
#define WM_OFF    19389728u     // f32[50000*100]  (ends 39,389,728)

// split 8 f32 into hi/lo bf16x8 via hw cvt
__device__ __forceinline__ void split8v(const float v[8], bf16x8 &h, bf16x8 &l) {
    #pragma unroll
    for (int e = 0; e < 8; e++) {
        __hip_bfloat16 hb = __float2bfloat16(v[e]);
        float hf = __bfloat162float(hb);
        __hip_bfloat16 lb = __float2bfloat16(v[e] - hf);
        h[e] = __builtin_bit_cast(short, hb);
        l[e] = __builtin_bit_cast(short, lb);
    }
}

// ---------- fused: tables (blocks 0..44) + MFMA weight frags (block 45) ----------
__global__ __launch_bounds__(256) void k_tabfrag(
    const float* __restrict__ champ, const float* __restrict__ role,
    const float* __restrict__ W1, const float* __restrict__ W2,
    const float* __restrict__ fc1W,
    float* __restrict__ chW, float* __restrict__ roW,
    bf16x8* __restrict__ w2f, bf16x8* __restrict__ f1f)
{
    if (blockIdx.x < 45) {
        int t = blockIdx.x * 256 + threadIdx.x;   // 11520 = 170*64 + 10*64 exactly
        if (t < 170 * 64) {
            int c = t >> 6, j = t & 63;
            float s = 0.f;
            #pragma unroll
            for (int k = 0; k < 32; k++) s += champ[c * 32 + k] * W1[k * 64 + j];
            chW[t] = s;
        } else {
            int t2 = t - 170 * 64;
            int r = t2 >> 6, j = t2 & 63;
            float s = 0.f;
            #pragma unroll
            for (int k = 0; k < 8; k++) s += role[r * 8 + k] * W1[(32 + k) * 64 + j];
            roW[t2] = s;
        }
    } else if (threadIdx.x < 64) {
        const int lane = threadIdx.x, q = lane >> 4, c = lane & 15;
        #pragma unroll
        for (int ks = 0; ks < 2; ks++)
        #pragma unroll
        for (int t = 0; t < 4; t++) {
            float v[8];
            #pragma unroll
            for (int e = 0; e < 8; e++) {
                int k = 32 * ks + (e < 4 ? 4 * q + e : 16 + 4 * q + (e - 4));
                v[e] = W2[k * 64 + 16 * t + c];
            }
            bf16x8 h, l; split8v(v, h, l);
            w2f[(ks * 4 + t) * 64 + lane] = h;
            w2f[(8 + ks * 4 + t) * 64 + lane] = l;
        }
        #pragma unroll
        for (int ks = 0; ks < 2; ks++)
        #pragma unroll
        for (int t = 0; t < 2; t++) {
            float v[8];
            #pragma unroll
            for (int e = 0; e < 8; e++) {
                int k = 32 * ks + (e < 4 ? 4 * q + e : 16 + 4 * q + (e - 4));
                v[e] = fc1W[k * 32 + 16 * t + c];
            }
            bf16x8 h, l; split8v(v, h, l);
            f1f[(ks * 2 + t) * 64 + lane] = h;
            f1f[(4 + ks * 2 + t) * 64 + lane] = l;
        }
    }
}

// ---------- phase A: partition via block-local counting sort + coalesced flush ----------
// Scattered 4B global writes cost ~25B/line-RMW each (R8: 100MB WRITE for 16MB
// payload). Fix: bucket-sort the block's 16384 records in LDS, then flush runs
// (mean 42 contiguous dwords) so the wave's stores form contiguous segments.
__global__ __launch_bounds__(512) void k_part(const int* __restrict__ ei,
                                              unsigned* __restrict__ rec,
                                              unsigned* __restrict__ tail) {
    __shared__ unsigned hist[NB];       // histogram, then scatter cursor
    __shared__ unsigned lofs[NB];       // local exclusive prefix
    __shared__ unsigned gbase[NB];      // global run base for this block
    __shared__ unsigned sorted[NPB];    // 64 KB bucket-sorted records
    const int tid = threadIdx.x;
    const int e0 = blockIdx.x * NPB;
    const int n = min(NPB, N_EDGES - e0);

    for (int i = tid; i < NB; i += 512) hist[i] = 0;
    __syncthreads();
    // pass 1: bucket histogram (dst only); bucket = dst/1280 == (dst/10)>>7
    for (int i = tid; i < n; i += 512) {
        unsigned d = (unsigned)ei[N_EDGES + e0 + i];
        atomicAdd(&hist[d / 1280u], 1u);
    }
    __syncthreads();
    // exclusive prefix over 391 buckets: wave 0, 7 buckets/lane + shfl scan
    if (tid < 64) {
        unsigned part = 0;
        #pragma unroll
        for (int j = 0; j < 7; j++) {
            int b = tid * 7 + j;
            if (b < NB) part += hist[b];
        }
        unsigned scan = part;
        #pragma unroll
        for (int off = 1; off < 64; off <<= 1) {
            unsigned t = __shfl_up(scan, off, 64);
            if (tid >= off) scan += t;
        }
        unsigned excl = scan - part;
        #pragma unroll
        for (int j = 0; j < 7; j++) {
            int b = tid * 7 + j;
            if (b < NB) { unsigned h = hist[b]; lofs[b] = excl; excl += h; }
        }
    }
    __syncthreads();
    // reserve global run space (hot 1.5KB atomics) + convert hist -> cursor
    for (int b = tid; b < NB; b += 512) {
        unsigned c = hist[b];
        gbase[b] = (unsigned)b * BCAP + (c ? atomicAdd(&tail[b], c) : 0u);
        hist[b] = lofs[b];
    }
    __syncthreads();
    // pass 2: scatter into LDS, bucket-sorted (edge chunk is L2-hot)
    for (int i = tid; i < n; i += 512) {
        unsigned s = (unsigned)ei[e0 + i];
        unsigned d = (unsigned)ei[N_EDGES + e0 + i];
        unsigned g = d / 10u;
        unsigned key = g * 100u + (d - g * 10u) * 10u + (s % 10u);
        unsigned pos = atomicAdd(&hist[g >> 7], 1u);
        sorted[pos] = key;
    }
    __syncthreads();
    // flush: element i -> gbase[b] + (i - lofs[b]); runs contiguous in LDS & global
    for (int i = tid; i < n; i += 512) {
        unsigned key = sorted[i];
        unsigned b = (key / 100u) >> 7;
        rec[gbase[b] + ((unsigned)i - lofs[b])] = key;
    }
}

// ---------- phase B: count in LDS + build normalized adjacency -> wmat ----------
__global__ __launch_bounds__(256) void k_count(const unsigned* __restrict__ rec,
                                               const unsigned* __restrict__ tail,
                                               float* __restrict__ wmat) {
    __shared__ unsigned cw[128 * 25];   // packed 4xu8 counts for 128 graphs
    const int tid = threadIdx.x;
    const unsigned b = blockIdx.x;

    for (int i = tid; i < 3200; i += 256) cw[i] = 0;
    __syncthreads();
    const unsigned n = tail[b];
    const unsigned base = b * BCAP;
    for (unsigned i = tid; i < n; i += 256) {
        unsigned key = rec[base + i];
        unsigned g = key / 100u;
        unsigned slot = key - g * 100u;
        atomicAdd(&cw[(g & 127u) * 25u + (slot >> 2)], 1u << (8u * (slot & 3u)));
    }
    __syncthreads();
    if (tid < 128) {
        unsigned g = b * 128u + (unsigned)tid;
        if (g < N_GRAPHS) {
            float c100[100];
            #pragma unroll
            for (int i = 0; i < 25; i++) {
                unsigned w = cw[tid * 25 + i];
                c100[4 * i + 0] = (float)(w & 255u);
                c100[4 * i + 1] = (float)((w >> 8) & 255u);
                c100[4 * i + 2] = (float)((w >> 16) & 255u);
                c100[4 * i + 3] = (float)(w >> 24);
            }
            float dinv[10];
            #pragma unroll
            for (int u = 0; u < 10; u++) {
                float s = 1.f;
                #pragma unroll
                for (int v = 0; v < 10; v++) s += c100[u * 10 + v];
                dinv[u] = rsqrtf(s);
            }
            #pragma unroll
            for (int u = 0; u < 10; u++)
                #pragma unroll
                for (int v = 0; v < 10; v++)
                    c100[u * 10 + v] = (c100[u * 10 + v] + (u == v ? 1.f : 0.f)) * dinv[u] * dinv[v];
            float4* wp = (float4*)(wmat + (size_t)g * 100);
            #pragma unroll
            for (int r = 0; r < 25; r++)
                wp[r] = make_float4(c100[4 * r], c100[4 * r + 1], c100[4 * r + 2], c100[4 * r + 3]);
        }
    }
}

// ---------- pass1: a1 = Wmat@hw + b1 via SGPR Wmat ; BN1 stats ----------
__global__ __launch_bounds__(256) void k_pass1(
    const int* __restrict__ x, const float* __restrict__ wmat,
    const float* __restrict__ chW, const float* __restrict__ roW,
    const float* __restrict__ W1, const float* __restrict__ b1,
    float* __restrict__ p1s, float* __restrict__ p1q)
{
    const int lane = threadIdx.x & 63;
    const int g = __builtin_amdgcn_readfirstlane(blockIdx.x * 4 + (threadIdx.x >> 6));
    const int* xg = x + g * 30;           // uniform -> s_load
    const float* wm = wmat + g * 100;     // uniform -> s_load

    const float w1t = W1[40 * 64 + lane];
    float hw[10];
    #pragma unroll
    for (int u = 0; u < 10; u++) {
        int cu = xg[u * 3 + 0];
        int ru = xg[u * 3 + 1];
        float tm = (float)xg[u * 3 + 2];
        hw[u] = chW[cu * 64 + lane] + roW[ru * 64 + lane] + tm * w1t;
    }
    const float b1v = b1[lane];
    float s = 0.f, ss = 0.f;
    #pragma unroll
    for (int u = 0; u < 10; u++) {
        float a = b1v;
        #pragma unroll
        for (int v = 0; v < 10; v++) a = fmaf(wm[u * 10 + v], hw[v], a);
        s += a; ss += a * a;
    }
    int slot = g & 127;
    atomicAdd(&p1s[slot * 64 + lane], s);
    atomicAdd(&p1q[slot * 64 + lane], ss);
}

// ---------- finalize BN1 (parallel) ----------
__global__ __launch_bounds__(1024) void k_fin1(
    const float* __restrict__ p1s, const float* __restrict__ p1q,
    const float* __restrict__ gamma, const float* __restrict__ beta,
    float* __restrict__ sc)
{
    __shared__ double rs[16][64], rq[16][64];
    int s = threadIdx.x >> 6, j = threadIdx.x & 63;
    double a = 0.0, b = 0.0;
    for (int k = s; k < 128; k += 16) { a += p1s[k * 64 + j]; b += p1q[k * 64 + j]; }
    rs[s][j] = a; rq[s][j] = b;
    __syncthreads();
    if (s == 0) {
        for (int k = 1; k < 16; k++) { a += rs[k][j]; b += rq[k][j]; }
        double mu = a / (double)N_NODES;
        double var = b / (double)N_NODES - mu * mu;
        float scl = gamma[j] * rsqrtf((float)var + 1e-5f);
        sc[j] = scl;
        sc[64 + j] = beta[j] - (float)mu * scl;
    }
}

// ---------- main pass: 4 graphs/wave; conv1+BN+relu, conv2, a2 MFMA, pool -> G ----------
__global__ __launch_bounds__(256) void k_main(
    const int* __restrict__ x, const float* __restrict__ wmat,
    const float* __restrict__ chW, const float* __restrict__ roW,
    const float* __restrict__ W1, const float* __restrict__ b1,
    const float* __restrict__ sc,
    const bf16x8* __restrict__ w2f, const float* __restrict__ b2,
    float* __restrict__ G)
{
    __shared__ float stage[4][1088];   // per-wave u2 tile [16 rows][68]

    const int w = threadIdx.x >> 6, lane = threadIdx.x & 63;
    const int q = lane >> 4, c = lane & 15;
    const int wid = __builtin_amdgcn_readfirstlane((int)blockIdx.x * 4 + w);

    float* up = stage[w];
    for (int i = lane; i < 408; i += 64) up[680 + i] = 0.f;   // zero pad rows 10..15

    const float w1t = W1[40 * 64 + lane];
    const float b1v = b1[lane];
    const float sc1 = sc[lane], sf1 = sc[64 + lane];
    float b2v[4];
    #pragma unroll
    for (int t = 0; t < 4; t++) b2v[t] = b2[16 * t + c];

    #pragma unroll 1
    for (int gi = 0; gi < 4; gi++) {
        const int g = wid * 4 + gi;
        const int* xg = x + g * 30;           // uniform -> s_load
        const float* wm = wmat + g * 100;     // uniform -> s_load

        float hw[10];
        #pragma unroll
        for (int u = 0; u < 10; u++) {
            int cu = xg[u * 3 + 0];
            int ru = xg[u * 3 + 1];
            float tm = (float)xg[u * 3 + 2];
            hw[u] = chW[cu * 64 + lane] + roW[ru * 64 + lane] + tm * w1t;
        }
        float h1[10];
        #pragma unroll
        for (int u = 0; u < 10; u++) {
            float a = b1v;
            #pragma unroll
            for (int v2 = 0; v2 < 10; v2++) a = fmaf(wm[u * 10 + v2], hw[v2], a);
            h1[u] = fmaxf(fmaf(a, sc1, sf1), 0.f);
        }
        #pragma unroll
        for (int u = 0; u < 10; u++) {
            float t = 0.f;
            #pragma unroll
            for (int v2 = 0; v2 < 10; v2++) t = fmaf(wm[u * 10 + v2], h1[v2], t);
            up[u * 68 + lane] = t;            // wave-private tile, no barrier
        }
        // a2 = u2 @ W2 via 3-product split MFMA (weights from global, L1-hot)
        f32x4 acc[4] = {f32x4{0.f,0.f,0.f,0.f}, f32x4{0.f,0.f,0.f,0.f},
                        f32x4{0.f,0.f,0.f,0.f}, f32x4{0.f,0.f,0.f,0.f}};
        const float4* rowp = (const float4*)(up + c * 68);
        #pragma unroll
        for (int ks = 0; ks < 2; ks++) {
            float4 A0 = rowp[8 * ks + q];
            float4 A1 = rowp[8 * ks + 4 + q];
            float av[8] = {A0.x, A0.y, A0.z, A0.w, A1.x, A1.y, A1.z, A1.w};
            bf16x8 ah, al; split8v(av, ah, al);
            #pragma unroll
            for (int t = 0; t < 4; t++) {
                bf16x8 bh = w2f[(ks * 4 + t) * 64 + lane];
                bf16x8 bl = w2f[(8 + ks * 4 + t) * 64 + lane];
                acc[t] = __builtin_amdgcn_mfma_f32_16x16x32_bf16(ah, bh, acc[t], 0, 0, 0);
                acc[t] = __builtin_amdgcn_mfma_f32_16x16x32_bf16(al, bh, acc[t], 0, 0, 0);
                acc[t] = __builtin_amdgcn_mfma_f32_16x16x32_bf16(ah, bl, acc[t], 0, 0, 0);
            }
        }
        // relu + masked mean-pool; C rows are nodes m = 4q+r
        float pool[4];
        #pragma unroll
        for (int t = 0; t < 4; t++) {
            float pt = 0.f;
            #pragma unroll
            for (int r = 0; r < 4; r++) {
                int m = 4 * q + r;
                float val = fmaxf(acc[t][r] + b2v[t], 0.f);
                pt += (m < 10) ? val : 0.f;
            }
            pt += __shfl_xor(pt, 16);
            pt += __shfl_xor(pt, 32);
            pool[t] = pt * 0.1f;
        }
        float gv = (q == 0) ? pool[0] : (q == 1) ? pool[1] : (q == 2) ? pool[2] : pool[3];
        G[(size_t)g * 64 + lane] = gv;        // coalesced 256B store
    }
}

// ---------- fc1 via MFMA over 16 pooled vectors per wave ; z + BN2 stats ----------
__global__ __launch_bounds__(256) void k_fc(
    const float* __restrict__ G, const bf16x8* __restrict__ f1f,
    const float* __restrict__ fc1b,
    float* __restrict__ zbuf, float* __restrict__ p2s, float* __restrict__ p2q)
{
    const int w = threadIdx.x >> 6, lane = threadIdx.x & 63;
    const int q = lane >> 4, c = lane & 15;
    const int wid = __builtin_amdgcn_readfirstlane((int)blockIdx.x * 4 + w);
    if (wid >= N_GRAPHS / 16) return;
    const int g0 = wid * 16;

    float f1bv[2];
    #pragma unroll
    for (int t = 0; t < 2; t++) f1bv[t] = fc1b[16 * t + c];

    f32x4 facc[2] = {f32x4{0.f,0.f,0.f,0.f}, f32x4{0.f,0.f,0.f,0.f}};
    const float* grow = G + (size_t)(g0 + c) * 64;
    #pragma unroll
    for (int ks = 0; ks < 2; ks++) {
        float4 G0 = *(const float4*)(grow + 32 * ks + 4 * q);
        float4 G1 = *(const float4*)(grow + 32 * ks + 16 + 4 * q);
        float gvv[8] = {G0.x, G0.y, G0.z, G0.w, G1.x, G1.y, G1.z, G1.w};
        bf16x8 gh, gl; split8v(gvv, gh, gl);
        #pragma unroll
        for (int t = 0; t < 2; t++) {
            bf16x8 fh = f1f[(ks * 2 + t) * 64 + lane];
            bf16x8 fl = f1f[(4 + ks * 2 + t) * 64 + lane];
            facc[t] = __builtin_amdgcn_mfma_f32_16x16x32_bf16(gh, fh, facc[t], 0, 0, 0);
            facc[t] = __builtin_amdgcn_mfma_f32_16x16x32_bf16(gl, fh, facc[t], 0, 0, 0);
            facc[t] = __builtin_amdgcn_mfma_f32_16x16x32_bf16(gh, fl, facc[t], 0, 0, 0);
        }
    }
    #pragma unroll
    for (int t = 0; t < 2; t++)
    #pragma unroll
    for (int r = 0; r < 4; r++) {
        int gg = g0 + 4 * q + r;
        float zv = facc[t][r] + f1bv[t];
        zbuf[gg * 32 + 16 * t + c] = zv;
        int slot = gg & 127;
        atomicAdd(&p2s[slot * 32 + 16 * t + c], zv);
        atomicAdd(&p2q[slot * 32 + 16 * t + c], zv * zv);
    }
}

// ---------- finalize BN2 (parallel) ----------
__global__ __launch_bounds__(512) void k_fin2(
    const float* __restrict__ p2s, const float* __restrict__ p2q,
    const float* __restrict__ gamma, const float* __restrict__ beta,
    float* __restrict__ sc)
{
    __shared__ double rs[16][32], rq[16][32];
    int s = threadIdx.x >> 5, j = threadIdx.x & 31;
    double a = 0.0, b = 0.0;
    for (int k = s; k < 128; k += 16) { a += p2s[k * 32 + j]; b += p2q[k * 32 + j]; }
    rs[s][j] = a; rq[s][j] = b;
    __syncthreads();
    if (s == 0) {
        for (int k = 1; k < 16; k++) { a += rs[k][j]; b += rq[k][j]; }
        double mu = a / (double)N_GRAPHS;
        double var = b / (double)N_GRAPHS - mu * mu;
        float scl = gamma[j] * rsqrtf((float)var + 1e-5f);
        sc[128 + j] = scl;
        sc[160 + j] = beta[j] - (float)mu * scl;
    }
}

// ---------- pass3: BN2 + relu + fc2 + sigmoid ----------
__global__ __launch_bounds__(256) void k_pass3(
    const float* __restrict__ z, const float* __restrict__ sc,
    const float* __restrict__ fc2W, const float* __restrict__ fc2b,
    float* __restrict__ out)
{
    int t = blockIdx.x * blockDim.x + threadIdx.x;
    int g = t >> 5, j = t & 31;
    float y = fmaxf(fmaf(z[g * 32 + j], sc[128 + j], sc[160 + j]), 0.f);
    float acc = y * fc2W[j];
    #pragma unroll
    for (int off = 16; off > 0; off >>= 1) acc += __shfl_xor(acc, off, 32);
    if (j == 0) out[g] = 1.0f / (1.0f + __expf(-(acc + fc2b[0])));
}

extern "C" void kernel_launch(void* const* d_in, const int* in_sizes, int n_in,
                              void* d_out, int out_size, void* d_ws, size_t ws_size,
                              hipStream_t stream) {
    const int*   x      = (const int*)d_in[0];
    const int*   ei     = (const int*)d_in[1];
    const float* champ  = (const float*)d_in[3];
    const float* role   = (const float*)d_in[4];
    const float* W1     = (const float*)d_in[5];
    const float* b1     = (const float*)d_in[6];
    const float* gamma1 = (const float*)d_in[7];
    const float* beta1  = (const float*)d_in[8];
    const float* W2     = (const float*)d_in[9];
    const float* b2     = (const float*)d_in[10];
    const float* fc1W   = (const float*)d_in[11];
    const float* fc1b   = (const float*)d_in[12];
    const float* gamma2 = (const float*)d_in[13];
    const float* beta2  = (const float*)d_in[14];
    const float* fc2W   = (const float*)d_in[15];
    const float* fc2b   = (const float*)d_in[16];
    float* out = (float*)d_out;

    char* ws = (char*)d_ws;
    unsigned* rec  = (unsigned*)(ws + REC_OFF);
    unsigned* tail = (unsigned*)(ws + TAIL_OFF);
    float* zbuf = (float*)(ws + ZB_OFF);
    float* G    = (float*)(ws + G_OFF);
    float* p1s  = (float*)(ws + P1S_OFF);
    float* p1q  = (float*)(ws + P1Q_OFF);
    float* p2s  = (float*)(ws + P2S_OFF);
    float* p2q  = (float*)(ws + P2Q_OFF);
    float* chW  = (float*)(ws + CHW_OFF);
    float* roW  = (float*)(ws + ROW_OFF);
    bf16x8* w2f = (bf16x8*)(ws + W2F_OFF);
    bf16x8* f1f = (bf16x8*)(ws + F1F_OFF);
    float* scb  = (float*)(ws + SC_OFF);
    float* wmat = (float*)(ws + WM_OFF);

    hipMemsetAsync(ws + TAIL_OFF, 0, ZERO_LEN, stream);
    k_tabfrag<<<46, 256, 0, stream>>>(champ, role, W1, W2, fc1W, chW, roW, w2f, f1f);
    k_part<<<NPART, 512, 0, stream>>>(ei, rec, tail);
    k_count<<<NB, 256, 0, stream>>>(rec, tail, wmat);
    k_pass1<<<N_GRAPHS / 4, 256, 0, stream>>>(x, wmat, chW, roW, W1, b1, p1s, p1q);
    k_fin1<<<1, 1024, 0, stream>>>(p1s, p1q, gamma1, beta1, scb);
    k_main<<<N_GRAPHS / 16, 256, 0, stream>>>(x, wmat, chW, roW, W1, b1, scb,
                                              w2f, b2, G);
    k_fc<<<(N_GRAPHS / 16 + 3) / 4, 256, 0, stream>>>(G, f1f, fc1b, zbuf, p2s, p2q);
    k_fin2<<<1, 512, 0, stream>>>(p2s, p2q, gamma2, beta2, scb);
    k_pass3<<<N_GRAPHS / 8, 256, 0, stream>>>(zbuf, scb, fc2W, fc2b, out);
}